// Round 10
// baseline (2371.809 us; speedup 1.0000x reference)
//
#include <hip/hip_runtime.h>
#include <stdint.h>
#include <math.h>

#define T_STEPS 599   // T-1 scan steps (x[1:])
#define T_RAW   600
#define NIN     16384
#define N0      4096
#define N1      1024
#define S0W     24    // padded words per S0 row: [pad0][19 spike words][4 zero]

typedef double d4 __attribute__((ext_vector_type(4)));

// ---- workspace layout (bytes) ----
static const size_t OFF_I0T = 0;
static const size_t SZ_I0T  = (size_t)T_STEPS * N0 * 4;      // 9,814,016
static const size_t OFF_S0B = OFF_I0T + SZ_I0T;
static const size_t SZ_S0B  = (size_t)N0 * S0W * 4;          // 393,216

// Relaxed barrier: LDS ordering only (lgkmcnt), NO vmcnt drain. Global loads
// target only the issuing wave's VGPRs -> no cross-wave hazard. Single asm
// block with memory clobber so no memory op is scheduled across it.
#define BARRIER_RELAXED() asm volatile("s_waitcnt lgkmcnt(0)\n\ts_barrier" ::: "memory")

// ========== Kernel 1: I0 = W0 @ X, fp64 MFMA, 2x2 wave split, depth-2 prefetch ==========
// Tile 32(M) x 64(N), BK=32, dbuf LDS. Wave (kh,nh): 32x32 quarter, k-half.
// NEW vs R9: (a) relaxed barriers (no vmcnt(0) drain at s_barrier);
// (b) prefetch depth 2: two named reg/pointer sets (A/B), chunk k+2 loads
// issue while chunk k computes -> ~2 MFMA phases of latency cover.
__global__ __launch_bounds__(256, 5) void gemm_i0_mfma(const float* __restrict__ W0,
                                                       const float* __restrict__ stim,
                                                       float* __restrict__ I0T) {
    __shared__ __align__(16) char smem[27904];
    float* As0 = (float*)(smem);            // 32*37*4 = 4736
    float* As1 = (float*)(smem + 4736);
    float* Bs0 = (float*)(smem + 9472);     // 32*72*4 = 9216
    float* Bs1 = (float*)(smem + 18688);
    const int tid  = threadIdx.x;
    const int lane = tid & 63;
    const int wid  = tid >> 6;
    const int kbase = 16 * (wid >> 1);      // k half: 0 or 16
    const int coff  = 32 * (wid & 1);       // tau half: 0 or 32
    // XCD-chunked bijective swizzle (1280 % 8 == 0)
    const int flat = blockIdx.x;
    const int idx  = (flat & 7) * 160 + (flat >> 3);
    const int n0   = (idx / 10) * 32;
    const int tau0 = (idx % 10) * 64;
    const int r15  = lane & 15;
    const int c    = lane >> 4;             // k-phase 0..3

    // ---- probe the C/D layout of v_mfma_f64_16x16x4f64 (proven R3) ----
    d4 zero = {0.0, 0.0, 0.0, 0.0};
    const double ap1 = (c == 0) ? 1.0 : 0.0;
    const double bp1 = (c == 0) ? (double)r15 : 0.0;
    d4 pcol = __builtin_amdgcn_mfma_f64_16x16x4f64(ap1, bp1, zero, 0, 0, 0);
    const double ap2 = (c == 0) ? (double)r15 : 0.0;
    const double bp2 = (c == 0) ? 1.0 : 0.0;
    d4 prow = __builtin_amdgcn_mfma_f64_16x16x4f64(ap2, bp2, zero, 0, 0, 0);
    int rowr[4], colr[4];
#pragma unroll
    for (int r = 0; r < 4; ++r) {
        int cc = (int)pcol[r]; cc = cc < 0 ? 0 : (cc > 15 ? 15 : cc);
        int rw = (int)prow[r]; rw = rw < 0 ? 0 : (rw > 15 ? 15 : rw);
        colr[r] = cc; rowr[r] = rw;
    }

    // ---- staging thread mapping ----
    const int ar  = tid >> 3;           // A row 0..31
    const int ac4 = (tid & 7) * 4;      // A k-col
    const int br  = tid >> 4;           // B k-row 0..15 (and +16)
    const int bc4 = (tid & 15) * 4;     // B tau-col
    const int t0g = tau0 + bc4;
    const bool fastB = (tau0 + 68) <= T_RAW;

    // two pointer sets, 2 chunks apart (advance +64 per load)
    const float* aP_A  = W0 + (size_t)(n0 + ar) * NIN + ac4;
    const float* bP0_A = stim + (size_t)br * T_RAW + t0g;
    const float* bP1_A = stim + (size_t)(br + 16) * T_RAW + t0g;
    const float* aP_B  = aP_A + 32;
    const float* bP0_B = bP0_A + 32 * T_RAW;
    const float* bP1_B = bP1_A + 32 * T_RAW;

    // two named staging reg sets (NO arrays)
    float4 aR_A, bRa_A, bRb_A;
    float4 aR_B, bRa_B, bRb_B;

#define LOAD_SET(S)                                                       \
    aR_##S = *reinterpret_cast<const float4*>(aP_##S);                    \
    if (fastB) {                                                          \
        float4 f0 = *reinterpret_cast<const float4*>(bP0_##S);            \
        float  e0 = bP0_##S[4];                                           \
        bRa_##S.x = f0.y; bRa_##S.y = f0.z; bRa_##S.z = f0.w; bRa_##S.w = e0; \
        float4 f1 = *reinterpret_cast<const float4*>(bP1_##S);            \
        float  e1 = bP1_##S[4];                                           \
        bRb_##S.x = f1.y; bRb_##S.y = f1.z; bRb_##S.z = f1.w; bRb_##S.w = e1; \
    } else {                                                              \
        bRa_##S.x = (t0g + 0 < T_STEPS) ? bP0_##S[1] : 0.0f;              \
        bRa_##S.y = (t0g + 1 < T_STEPS) ? bP0_##S[2] : 0.0f;              \
        bRa_##S.z = (t0g + 2 < T_STEPS) ? bP0_##S[3] : 0.0f;              \
        bRa_##S.w = (t0g + 3 < T_STEPS) ? bP0_##S[4] : 0.0f;              \
        bRb_##S.x = (t0g + 0 < T_STEPS) ? bP1_##S[1] : 0.0f;              \
        bRb_##S.y = (t0g + 1 < T_STEPS) ? bP1_##S[2] : 0.0f;              \
        bRb_##S.z = (t0g + 2 < T_STEPS) ? bP1_##S[3] : 0.0f;              \
        bRb_##S.w = (t0g + 3 < T_STEPS) ? bP1_##S[4] : 0.0f;              \
    }                                                                     \
    aP_##S += 64; bP0_##S += 64 * T_RAW; bP1_##S += 64 * T_RAW;

#define STAGE_SET(S, AS, BS)                                              \
    *reinterpret_cast<float4*>(&AS[ar * 37 + ac4]) = aR_##S;              \
    *reinterpret_cast<float4*>(&BS[br * 72 + bc4]) = bRa_##S;             \
    *reinterpret_cast<float4*>(&BS[(br + 16) * 72 + bc4]) = bRb_##S;

#define KSTEP(AS, BS, KK)                                                 \
    {                                                                     \
        const double a0 = (double)AS[r15 * 37 + (KK)];                    \
        const double a1 = (double)AS[(16 + r15) * 37 + (KK)];             \
        const double b0 = (double)BS[(KK) * 72 + coff + r15];             \
        const double b1 = (double)BS[(KK) * 72 + coff + 16 + r15];        \
        c00 = __builtin_amdgcn_mfma_f64_16x16x4f64(a0, b0, c00, 0, 0, 0); \
        c01 = __builtin_amdgcn_mfma_f64_16x16x4f64(a0, b1, c01, 0, 0, 0); \
        c10 = __builtin_amdgcn_mfma_f64_16x16x4f64(a1, b0, c10, 0, 0, 0); \
        c11 = __builtin_amdgcn_mfma_f64_16x16x4f64(a1, b1, c11, 0, 0, 0); \
    }

#define MFMA_PHASE(AS, BS)                                                \
    __builtin_amdgcn_s_setprio(1);                                        \
    KSTEP(AS, BS, kbase + c);                                             \
    KSTEP(AS, BS, kbase + 4 + c);                                         \
    KSTEP(AS, BS, kbase + 8 + c);                                         \
    KSTEP(AS, BS, kbase + 12 + c);                                        \
    __builtin_amdgcn_s_setprio(0);

    // 4 named accumulators: c{p}{m}: rows p*16+, cols coff + m*16+
    d4 c00 = {0,0,0,0}, c01 = {0,0,0,0};
    d4 c10 = {0,0,0,0}, c11 = {0,0,0,0};

    // prologue: chunk 0 -> set A, chunk 1 -> set B
    LOAD_SET(A);
    LOAD_SET(B);

    // 512 chunks of BK=32, 2 per iteration. Iter i: phase0 stages chunk 2i
    // (set A) and loads chunk 2i+2; phase1 stages 2i+1 (set B), loads 2i+3.
    for (int chp = 0; chp < 256; ++chp) {
        STAGE_SET(A, As0, Bs0);
        BARRIER_RELAXED();
        if (chp < 255) { LOAD_SET(A); }
        MFMA_PHASE(As0, Bs0);

        STAGE_SET(B, As1, Bs1);
        BARRIER_RELAXED();
        if (chp < 255) { LOAD_SET(B); }
        MFMA_PHASE(As1, Bs1);
    }
#undef LOAD_SET
#undef STAGE_SET
#undef KSTEP
#undef MFMA_PHASE

    // ---- cross-wave reduction over kh: Cred[col][row] aliases staging LDS ----
    __syncthreads();                      // k-loop fully done (vmcnt=0 naturally)
    double* Cred = (double*)smem;         // 64*32*8 = 16384 <= 27904

#define CRED_OP(OP)                                                       \
    _Pragma("unroll")                                                     \
    for (int r = 0; r < 4; ++r) {                                         \
        const int ro = rowr[r], co = coff + colr[r];                      \
        Cred[(co     ) * 32 + ro     ] OP c00[r];                         \
        Cred[(co + 16) * 32 + ro     ] OP c01[r];                         \
        Cred[(co     ) * 32 + ro + 16] OP c10[r];                         \
        Cred[(co + 16) * 32 + ro + 16] OP c11[r];                         \
    }

    if (wid < 2)  { CRED_OP(=) }          // kh=0: waves 0,1 (disjoint cols)
    __syncthreads();
    if (wid >= 2) { CRED_OP(+=) }         // kh=1: waves 2,3 add
    __syncthreads();
#undef CRED_OP

    // ---- store: thread -> (tau col, 8-row strip), float4 x2 ----
    const int scol = tid >> 2;            // 0..63
    const int srow = (tid & 3) * 8;       // 0,8,16,24
    const int tcol = tau0 + scol;
    if (tcol < T_STEPS) {
        const double* cp = &Cred[scol * 32 + srow];
        float4 o0, o1;
        o0.x = (float)cp[0]; o0.y = (float)cp[1]; o0.z = (float)cp[2]; o0.w = (float)cp[3];
        o1.x = (float)cp[4]; o1.y = (float)cp[5]; o1.z = (float)cp[6]; o1.w = (float)cp[7];
        float* op = &I0T[(size_t)tcol * N0 + n0 + srow];
        *reinterpret_cast<float4*>(op)     = o0;
        *reinterpret_cast<float4*>(op + 4) = o1;
    }
}

// ====== Kernel 2: layer-0 LIF scan -> padded bitpacked S0 (unrolled x8) ======
// 64 blocks x 64 threads: spreads the serial scan over 64 CUs (vs 16).
__global__ void lif0(const float* __restrict__ I0T, uint32_t* __restrict__ S0P) {
#pragma clang fp contract(off)
    const int n = blockIdx.x * 64 + threadIdx.x;   // 0..4095
    uint32_t* rowp = S0P + n * S0W;
    rowp[0] = 0u;
    rowp[20] = 0u; rowp[21] = 0u; rowp[22] = 0u; rowp[23] = 0u;
    float v = 0.0f;
    uint32_t word = 0;
    int t = 0;
    for (; t + 8 <= T_STEPS; t += 8) {
        float I[8];
#pragma unroll
        for (int u = 0; u < 8; ++u) I[u] = I0T[(size_t)(t + u) * N0 + n];
#pragma unroll
        for (int u = 0; u < 8; ++u) {
            const int tt = t + u;
            float a = v * 0.9f;        // separate rounding (match jnp)
            v = a + I[u];
            if (v >= 1.0f) { word |= (1u << (tt & 31)); v = 0.0f; }
            if ((tt & 31) == 31) { rowp[1 + (tt >> 5)] = word; word = 0; }
        }
    }
    for (; t < T_STEPS; ++t) {
        float I = I0T[(size_t)t * N0 + n];
        float a = v * 0.9f;
        v = a + I;
        if (v >= 1.0f) { word |= (1u << (t & 31)); v = 0.0f; }
        if ((t & 31) == 31) { rowp[1 + (t >> 5)] = word; word = 0; }
    }
    rowp[1 + (T_STEPS >> 5)] = word;   // word 18 (bits 576..598)
}

// ====== Kernel 3: fused gather + layer-1 LIF + S1 output ======
// Block j: I1 row computed into LDS (no global round-trip), then thread 0
// runs the 599-step serial LIF scan and writes S1 floats directly to out.
__global__ __launch_bounds__(128) void gather_lif1(const float* __restrict__ W1,
                                                   const int* __restrict__ delays,
                                                   const uint32_t* __restrict__ S0P,
                                                   float* __restrict__ out) {
#pragma clang fp contract(off)
    __shared__ double  wl[N0];      // 32 KB
    __shared__ uint8_t dl[N0];      // 4 KB
    __shared__ float   i1row[T_STEPS + 1];
    const int j   = blockIdx.x;
    const int tid = threadIdx.x;
    for (int q = tid; q < N0 / 4; q += 128) {
        const float4 w4 = *reinterpret_cast<const float4*>(&W1[(size_t)j * N0 + 4 * q]);
        wl[4 * q + 0] = (double)w4.x; wl[4 * q + 1] = (double)w4.y;
        wl[4 * q + 2] = (double)w4.z; wl[4 * q + 3] = (double)w4.w;
        const int4 dv = *reinterpret_cast<const int4*>(&delays[(size_t)j * N0 + 4 * q]);
        dl[4 * q + 0] = (uint8_t)dv.x; dl[4 * q + 1] = (uint8_t)dv.y;
        dl[4 * q + 2] = (uint8_t)dv.z; dl[4 * q + 3] = (uint8_t)dv.w;
    }
    __syncthreads();
    const int t0 = tid;                         // 0..127
    const bool has4 = (t0 + 512) < T_STEPS;     // t0 < 87
    double a0 = 0.0, a1 = 0.0, a2 = 0.0, a3 = 0.0, a4 = 0.0;
    const uint32_t* rp0 = S0P;
#pragma unroll 2
    for (int i = 0; i < N0; ++i) {
        const int s   = t0 - (int)dl[i];        // in [-15, 127]
        const double w = wl[i];
        const int idx = (s >> 5) + 1;           // 0..4
        const int bit = s & 31;
        const uint32_t r0 = rp0[idx];
        const uint32_t r1 = rp0[idx + 4];
        const uint32_t r2 = rp0[idx + 8];
        const uint32_t r3 = rp0[idx + 12];
        const uint32_t r4 = rp0[idx + 16];
        a0 = fma((double)((r0 >> bit) & 1u), w, a0);
        a1 = fma((double)((r1 >> bit) & 1u), w, a1);
        a2 = fma((double)((r2 >> bit) & 1u), w, a2);
        a3 = fma((double)((r3 >> bit) & 1u), w, a3);
        a4 = fma((double)((r4 >> bit) & 1u), w, a4);
        rp0 += S0W;
    }
    i1row[t0]       = (float)a0;
    i1row[t0 + 128] = (float)a1;
    i1row[t0 + 256] = (float)a2;
    i1row[t0 + 384] = (float)a3;
    if (has4) i1row[t0 + 512] = (float)a4;
    __syncthreads();
    if (tid == 0) {
        float* o = out + (size_t)N0 * T_STEPS + (size_t)j * T_STEPS;
        float v = 0.0f;
        for (int t = 0; t < T_STEPS; ++t) {
            float a = v * 0.9f;                 // separate rounding (match jnp)
            v = a + i1row[t];
            float s = 0.0f;
            if (v >= 1.0f) { s = 1.0f; v = 0.0f; }
            o[t] = s;
        }
    }
}

// ====== Kernel 4: expand S0 bits -> fp32 output (S0.T) ======
__global__ void expand_out(const uint32_t* __restrict__ S0P,
                           float* __restrict__ out) {
    const int t = blockIdx.x * 256 + threadIdx.x;
    if (t >= T_STEPS) return;
    const int row = blockIdx.y;
    uint32_t b = (S0P[row * S0W + 1 + (t >> 5)] >> (t & 31)) & 1u;
    out[(size_t)row * T_STEPS + t] = (float)b;
}

extern "C" void kernel_launch(void* const* d_in, const int* in_sizes, int n_in,
                              void* d_out, int out_size, void* d_ws, size_t ws_size,
                              hipStream_t stream) {
    const float* stim   = (const float*)d_in[0];   // 128*128*600
    const float* W0     = (const float*)d_in[1];   // 4096*16384
    const float* W1     = (const float*)d_in[2];   // 1024*4096
    const int*   delays = (const int*)d_in[3];     // 1024*4096

    char* ws = (char*)d_ws;
    float*    I0T  = (float*)(ws + OFF_I0T);
    uint32_t* S0b  = (uint32_t*)(ws + OFF_S0B);
    float*    out  = (float*)d_out;

    hipLaunchKernelGGL(gemm_i0_mfma, dim3(1280),   dim3(256), 0, stream, W0, stim, I0T);
    hipLaunchKernelGGL(lif0,         dim3(64),     dim3(64),  0, stream, I0T, S0b);
    hipLaunchKernelGGL(gather_lif1,  dim3(1024),   dim3(128), 0, stream, W1, delays, S0b, out);
    hipLaunchKernelGGL(expand_out,   dim3(3, N0),  dim3(256), 0, stream, S0b, out);
}

// Round 11
// 2212.249 us; speedup vs baseline: 1.0721x; 1.0721x over previous
//
#include <hip/hip_runtime.h>
#include <stdint.h>
#include <math.h>

#define T_STEPS 599   // T-1 scan steps (x[1:])
#define T_RAW   600
#define NIN     16384
#define N0      4096
#define N1      1024
#define S0W     24    // padded words per S0 row: [pad0][19 spike words][4 zero]
#define TAUP    640   // padded tau extent of Xt

typedef double d4 __attribute__((ext_vector_type(4)));

// ---- workspace layout (bytes) ----
static const size_t OFF_I0T = 0;
static const size_t SZ_I0T  = (size_t)T_STEPS * N0 * 4;      // 9,814,016
static const size_t OFF_S0B = OFF_I0T + SZ_I0T;
static const size_t SZ_S0B  = (size_t)N0 * S0W * 4;          // 393,216
static const size_t OFF_XT  = OFF_S0B + SZ_S0B;
static const size_t SZ_XT   = (size_t)TAUP * NIN * 4;        // 41,943,040 (~52.3 MB total)

// ====== Kernel 0: transpose stim[k][tau] -> Xt[tau][k] (bakes +1 shift, zero pad) ======
__global__ __launch_bounds__(256) void transpose_stim(const float* __restrict__ stim,
                                                      float* __restrict__ Xt) {
    __shared__ float T[64][65];
    const int tau0 = blockIdx.x * 64;   // 0..576 (10 blocks)
    const int k0   = blockIdx.y * 64;   // 0..16320 (256 blocks)
    const int tid  = threadIdx.x;
    // load: thread (kk = tid>>2, tau_local = (tid&3) + 4q), q = 0..15
    const int kk = tid >> 2;
    const int tb = tid & 3;
#pragma unroll
    for (int q = 0; q < 16; ++q) {
        const int tl = tb + 4 * q;
        const int tg = tau0 + tl;                 // Xt tau index
        float v = 0.0f;
        if (tg <= T_STEPS - 1) v = stim[(size_t)(k0 + kk) * T_RAW + tg + 1];
        T[kk][tl] = v;
    }
    __syncthreads();
    // store: thread (tt = tid>>2, k_local = (tid&3)*16 + 4j + e), 4 x b128
    const int tt = tid >> 2;
    const int kq = (tid & 3) * 16;
#pragma unroll
    for (int j = 0; j < 4; ++j) {
        const int kl = kq + 4 * j;
        float4 o;
        o.x = T[kl + 0][tt]; o.y = T[kl + 1][tt];
        o.z = T[kl + 2][tt]; o.w = T[kl + 3][tt];
        *reinterpret_cast<float4*>(&Xt[(size_t)(tau0 + tt) * NIN + k0 + kl]) = o;
    }
}

// ====== Kernel 1 (fast): I0 = W0 @ X, fp64 MFMA, all-b128 LDS reads ======
// Tile 32(M) x 64(N), BK=32, dbuf. Wave (kh,nh): k-half kbase, tau-half coff.
// k-reindex: MFMA m sums k = kbase + 4c + m (slot c) -> lane reads 4
// consecutive k as ONE ds_read_b128 for BOTH A ([n][k]) and B (Bt[tau][k]).
// Pad 44 floats: rows 176B (16B-aligned), banks (12*r+4c)%32 -> 2-way max.
// Loop structure = proven R9: STAGE -> __syncthreads -> LOAD_NEXT -> MFMA.
__global__ __launch_bounds__(256, 4) void gemm_i0_xt(const float* __restrict__ W0,
                                                     const float* __restrict__ Xt,
                                                     float* __restrict__ I0T) {
    __shared__ __align__(16) char smem[33792];
    float* As0 = (float*)(smem);             // 32*44*4 = 5632
    float* As1 = (float*)(smem + 5632);
    float* Bt0 = (float*)(smem + 11264);     // 64*44*4 = 11264
    float* Bt1 = (float*)(smem + 22528);
    const int tid  = threadIdx.x;
    const int lane = tid & 63;
    const int wid  = tid >> 6;
    const int kbase = 16 * (wid >> 1);       // k half: 0 or 16
    const int coff  = 32 * (wid & 1);        // tau half: 0 or 32
    const int flat = blockIdx.x;
    const int idx  = (flat & 7) * 160 + (flat >> 3);   // XCD swizzle (1280%8==0)
    const int n0   = (idx / 10) * 32;
    const int tau0 = (idx % 10) * 64;
    const int r15  = lane & 15;
    const int c    = lane >> 4;              // MFMA slot 0..3

    // ---- probe the C/D layout of v_mfma_f64_16x16x4f64 (proven R3) ----
    d4 zero = {0.0, 0.0, 0.0, 0.0};
    const double ap1 = (c == 0) ? 1.0 : 0.0;
    const double bp1 = (c == 0) ? (double)r15 : 0.0;
    d4 pcol = __builtin_amdgcn_mfma_f64_16x16x4f64(ap1, bp1, zero, 0, 0, 0);
    const double ap2 = (c == 0) ? (double)r15 : 0.0;
    const double bp2 = (c == 0) ? 1.0 : 0.0;
    d4 prow = __builtin_amdgcn_mfma_f64_16x16x4f64(ap2, bp2, zero, 0, 0, 0);
    int rowr[4], colr[4];
#pragma unroll
    for (int r = 0; r < 4; ++r) {
        int cc = (int)pcol[r]; cc = cc < 0 ? 0 : (cc > 15 ? 15 : cc);
        int rw = (int)prow[r]; rw = rw < 0 ? 0 : (rw > 15 ? 15 : rw);
        colr[r] = cc; rowr[r] = rw;
    }

    // ---- staging maps ----
    const int ar   = tid >> 3;           // A row 0..31
    const int ac4  = (tid & 7) * 4;      // A k-col (float4)
    const int btau = tid >> 2;           // B tau row 0..63
    const int bk8  = (tid & 3) * 8;      // B k-col base (2 float4)

    const float* aP  = W0 + (size_t)(n0 + ar) * NIN + ac4;
    const float* xP  = Xt + (size_t)(tau0 + btau) * NIN + bk8;

    float4 aR, bR0, bR1;                 // named staging regs (NO arrays)

#define XLOAD()                                                           \
    aR  = *reinterpret_cast<const float4*>(aP);                           \
    bR0 = *reinterpret_cast<const float4*>(xP);                           \
    bR1 = *reinterpret_cast<const float4*>(xP + 4);                       \
    aP += 32; xP += 32;

#define XSTAGE(AS, BS)                                                    \
    *reinterpret_cast<float4*>(&AS[ar * 44 + ac4]) = aR;                  \
    *reinterpret_cast<float4*>(&BS[btau * 44 + bk8]) = bR0;               \
    *reinterpret_cast<float4*>(&BS[btau * 44 + bk8 + 4]) = bR1;

    // 4 accumulators: c{p}{m}: rows p*16+, taus coff + m*16+
    d4 c00 = {0,0,0,0}, c01 = {0,0,0,0};
    d4 c10 = {0,0,0,0}, c11 = {0,0,0,0};

#define XMFMA(AS, BS)                                                     \
    {                                                                     \
        __builtin_amdgcn_s_setprio(1);                                    \
        const float4 a0f = *reinterpret_cast<const float4*>(&AS[r15 * 44 + kbase + 4 * c]);        \
        const float4 a1f = *reinterpret_cast<const float4*>(&AS[(16 + r15) * 44 + kbase + 4 * c]); \
        const float4 b0f = *reinterpret_cast<const float4*>(&BS[(coff + r15) * 44 + kbase + 4 * c]);      \
        const float4 b1f = *reinterpret_cast<const float4*>(&BS[(coff + 16 + r15) * 44 + kbase + 4 * c]); \
        c00 = __builtin_amdgcn_mfma_f64_16x16x4f64((double)a0f.x, (double)b0f.x, c00, 0, 0, 0);    \
        c01 = __builtin_amdgcn_mfma_f64_16x16x4f64((double)a0f.x, (double)b1f.x, c01, 0, 0, 0);    \
        c10 = __builtin_amdgcn_mfma_f64_16x16x4f64((double)a1f.x, (double)b0f.x, c10, 0, 0, 0);    \
        c11 = __builtin_amdgcn_mfma_f64_16x16x4f64((double)a1f.x, (double)b1f.x, c11, 0, 0, 0);    \
        c00 = __builtin_amdgcn_mfma_f64_16x16x4f64((double)a0f.y, (double)b0f.y, c00, 0, 0, 0);    \
        c01 = __builtin_amdgcn_mfma_f64_16x16x4f64((double)a0f.y, (double)b1f.y, c01, 0, 0, 0);    \
        c10 = __builtin_amdgcn_mfma_f64_16x16x4f64((double)a1f.y, (double)b0f.y, c10, 0, 0, 0);    \
        c11 = __builtin_amdgcn_mfma_f64_16x16x4f64((double)a1f.y, (double)b1f.y, c11, 0, 0, 0);    \
        c00 = __builtin_amdgcn_mfma_f64_16x16x4f64((double)a0f.z, (double)b0f.z, c00, 0, 0, 0);    \
        c01 = __builtin_amdgcn_mfma_f64_16x16x4f64((double)a0f.z, (double)b1f.z, c01, 0, 0, 0);    \
        c10 = __builtin_amdgcn_mfma_f64_16x16x4f64((double)a1f.z, (double)b0f.z, c10, 0, 0, 0);    \
        c11 = __builtin_amdgcn_mfma_f64_16x16x4f64((double)a1f.z, (double)b1f.z, c11, 0, 0, 0);    \
        c00 = __builtin_amdgcn_mfma_f64_16x16x4f64((double)a0f.w, (double)b0f.w, c00, 0, 0, 0);    \
        c01 = __builtin_amdgcn_mfma_f64_16x16x4f64((double)a0f.w, (double)b1f.w, c01, 0, 0, 0);    \
        c10 = __builtin_amdgcn_mfma_f64_16x16x4f64((double)a1f.w, (double)b0f.w, c10, 0, 0, 0);    \
        c11 = __builtin_amdgcn_mfma_f64_16x16x4f64((double)a1f.w, (double)b1f.w, c11, 0, 0, 0);    \
        __builtin_amdgcn_s_setprio(0);                                    \
    }

    XLOAD();                             // prologue: chunk 0
    for (int chp = 0; chp < 256; ++chp) {
        XSTAGE(As0, Bt0);
        __syncthreads();
        XLOAD();
        XMFMA(As0, Bt0);
        XSTAGE(As1, Bt1);
        __syncthreads();
        if (chp + 1 < 256) { XLOAD(); }
        XMFMA(As1, Bt1);
    }
#undef XLOAD
#undef XSTAGE
#undef XMFMA

    // ---- cross-wave reduction over kh: Cred[col][row] aliases staging LDS ----
    __syncthreads();
    double* Cred = (double*)smem;        // 64*32*8 = 16384 <= 33792

#define CRED_OP(OP)                                                       \
    _Pragma("unroll")                                                     \
    for (int r = 0; r < 4; ++r) {                                         \
        const int ro = rowr[r], co = coff + colr[r];                      \
        Cred[(co     ) * 32 + ro     ] OP c00[r];                         \
        Cred[(co + 16) * 32 + ro     ] OP c01[r];                         \
        Cred[(co     ) * 32 + ro + 16] OP c10[r];                         \
        Cred[(co + 16) * 32 + ro + 16] OP c11[r];                         \
    }
    if (wid < 2)  { CRED_OP(=) }
    __syncthreads();
    if (wid >= 2) { CRED_OP(+=) }
    __syncthreads();
#undef CRED_OP

    const int scol = tid >> 2;
    const int srow = (tid & 3) * 8;
    const int tcol = tau0 + scol;
    if (tcol < T_STEPS) {
        const double* cp = &Cred[scol * 32 + srow];
        float4 o0, o1;
        o0.x = (float)cp[0]; o0.y = (float)cp[1]; o0.z = (float)cp[2]; o0.w = (float)cp[3];
        o1.x = (float)cp[4]; o1.y = (float)cp[5]; o1.z = (float)cp[6]; o1.w = (float)cp[7];
        float* op = &I0T[(size_t)tcol * N0 + n0 + srow];
        *reinterpret_cast<float4*>(op)     = o0;
        *reinterpret_cast<float4*>(op + 4) = o1;
    }
}

// ====== Kernel 1 (fallback, R9-exact): used only if ws too small for Xt ======
__global__ __launch_bounds__(256, 5) void gemm_i0_fb(const float* __restrict__ W0,
                                                     const float* __restrict__ stim,
                                                     float* __restrict__ I0T) {
    __shared__ __align__(16) char smem[27904];
    float* As0 = (float*)(smem);
    float* As1 = (float*)(smem + 4736);
    float* Bs0 = (float*)(smem + 9472);
    float* Bs1 = (float*)(smem + 18688);
    const int tid  = threadIdx.x;
    const int lane = tid & 63;
    const int wid  = tid >> 6;
    const int kbase = 16 * (wid >> 1);
    const int coff  = 32 * (wid & 1);
    const int flat = blockIdx.x;
    const int idx  = (flat & 7) * 160 + (flat >> 3);
    const int n0   = (idx / 10) * 32;
    const int tau0 = (idx % 10) * 64;
    const int r15  = lane & 15;
    const int c    = lane >> 4;
    d4 zero = {0.0, 0.0, 0.0, 0.0};
    const double ap1 = (c == 0) ? 1.0 : 0.0;
    const double bp1 = (c == 0) ? (double)r15 : 0.0;
    d4 pcol = __builtin_amdgcn_mfma_f64_16x16x4f64(ap1, bp1, zero, 0, 0, 0);
    const double ap2 = (c == 0) ? (double)r15 : 0.0;
    const double bp2 = (c == 0) ? 1.0 : 0.0;
    d4 prow = __builtin_amdgcn_mfma_f64_16x16x4f64(ap2, bp2, zero, 0, 0, 0);
    int rowr[4], colr[4];
#pragma unroll
    for (int r = 0; r < 4; ++r) {
        int cc = (int)pcol[r]; cc = cc < 0 ? 0 : (cc > 15 ? 15 : cc);
        int rw = (int)prow[r]; rw = rw < 0 ? 0 : (rw > 15 ? 15 : rw);
        colr[r] = cc; rowr[r] = rw;
    }
    const int ar  = tid >> 3;
    const int ac4 = (tid & 7) * 4;
    const int br  = tid >> 4;
    const int bc4 = (tid & 15) * 4;
    const int t0g = tau0 + bc4;
    const bool fastB = (tau0 + 68) <= T_RAW;
    const float* aP  = W0 + (size_t)(n0 + ar) * NIN + ac4;
    const float* bP0 = stim + (size_t)br * T_RAW + t0g;
    const float* bP1 = stim + (size_t)(br + 16) * T_RAW + t0g;
    float4 aR, bRa, bRb;
#define FLOAD()                                                           \
    aR = *reinterpret_cast<const float4*>(aP);                            \
    if (fastB) {                                                          \
        float4 f0 = *reinterpret_cast<const float4*>(bP0);                \
        float  e0 = bP0[4];                                               \
        bRa.x = f0.y; bRa.y = f0.z; bRa.z = f0.w; bRa.w = e0;             \
        float4 f1 = *reinterpret_cast<const float4*>(bP1);                \
        float  e1 = bP1[4];                                               \
        bRb.x = f1.y; bRb.y = f1.z; bRb.z = f1.w; bRb.w = e1;             \
    } else {                                                              \
        bRa.x = (t0g + 0 < T_STEPS) ? bP0[1] : 0.0f;                      \
        bRa.y = (t0g + 1 < T_STEPS) ? bP0[2] : 0.0f;                      \
        bRa.z = (t0g + 2 < T_STEPS) ? bP0[3] : 0.0f;                      \
        bRa.w = (t0g + 3 < T_STEPS) ? bP0[4] : 0.0f;                      \
        bRb.x = (t0g + 0 < T_STEPS) ? bP1[1] : 0.0f;                      \
        bRb.y = (t0g + 1 < T_STEPS) ? bP1[2] : 0.0f;                      \
        bRb.z = (t0g + 2 < T_STEPS) ? bP1[3] : 0.0f;                      \
        bRb.w = (t0g + 3 < T_STEPS) ? bP1[4] : 0.0f;                      \
    }                                                                     \
    aP += 32; bP0 += 32 * T_RAW; bP1 += 32 * T_RAW;
#define FSTAGE(AS, BS)                                                    \
    *reinterpret_cast<float4*>(&AS[ar * 37 + ac4]) = aR;                  \
    *reinterpret_cast<float4*>(&BS[br * 72 + bc4]) = bRa;                 \
    *reinterpret_cast<float4*>(&BS[(br + 16) * 72 + bc4]) = bRb;
#define FKSTEP(AS, BS, KK)                                                \
    {                                                                     \
        const double a0 = (double)AS[r15 * 37 + (KK)];                    \
        const double a1 = (double)AS[(16 + r15) * 37 + (KK)];             \
        const double b0 = (double)BS[(KK) * 72 + coff + r15];             \
        const double b1 = (double)BS[(KK) * 72 + coff + 16 + r15];        \
        c00 = __builtin_amdgcn_mfma_f64_16x16x4f64(a0, b0, c00, 0, 0, 0); \
        c01 = __builtin_amdgcn_mfma_f64_16x16x4f64(a0, b1, c01, 0, 0, 0); \
        c10 = __builtin_amdgcn_mfma_f64_16x16x4f64(a1, b0, c10, 0, 0, 0); \
        c11 = __builtin_amdgcn_mfma_f64_16x16x4f64(a1, b1, c11, 0, 0, 0); \
    }
#define FMFMA(AS, BS)                                                     \
    __builtin_amdgcn_s_setprio(1);                                        \
    FKSTEP(AS, BS, kbase + c);                                            \
    FKSTEP(AS, BS, kbase + 4 + c);                                        \
    FKSTEP(AS, BS, kbase + 8 + c);                                        \
    FKSTEP(AS, BS, kbase + 12 + c);                                       \
    __builtin_amdgcn_s_setprio(0);
    d4 c00 = {0,0,0,0}, c01 = {0,0,0,0};
    d4 c10 = {0,0,0,0}, c11 = {0,0,0,0};
    FLOAD();
    for (int chp = 0; chp < 256; ++chp) {
        FSTAGE(As0, Bs0);
        __syncthreads();
        FLOAD();
        FMFMA(As0, Bs0);
        FSTAGE(As1, Bs1);
        __syncthreads();
        if (chp + 1 < 256) { FLOAD(); }
        FMFMA(As1, Bs1);
    }
#undef FLOAD
#undef FSTAGE
#undef FKSTEP
#undef FMFMA
    __syncthreads();
    double* Cred = (double*)smem;
#define CRED_OP(OP)                                                       \
    _Pragma("unroll")                                                     \
    for (int r = 0; r < 4; ++r) {                                         \
        const int ro = rowr[r], co = coff + colr[r];                      \
        Cred[(co     ) * 32 + ro     ] OP c00[r];                         \
        Cred[(co + 16) * 32 + ro     ] OP c01[r];                         \
        Cred[(co     ) * 32 + ro + 16] OP c10[r];                         \
        Cred[(co + 16) * 32 + ro + 16] OP c11[r];                         \
    }
    if (wid < 2)  { CRED_OP(=) }
    __syncthreads();
    if (wid >= 2) { CRED_OP(+=) }
    __syncthreads();
#undef CRED_OP
    const int scol = tid >> 2;
    const int srow = (tid & 3) * 8;
    const int tcol = tau0 + scol;
    if (tcol < T_STEPS) {
        const double* cp = &Cred[scol * 32 + srow];
        float4 o0, o1;
        o0.x = (float)cp[0]; o0.y = (float)cp[1]; o0.z = (float)cp[2]; o0.w = (float)cp[3];
        o1.x = (float)cp[4]; o1.y = (float)cp[5]; o1.z = (float)cp[6]; o1.w = (float)cp[7];
        float* op = &I0T[(size_t)tcol * N0 + n0 + srow];
        *reinterpret_cast<float4*>(op)     = o0;
        *reinterpret_cast<float4*>(op + 4) = o1;
    }
}

// ====== Kernel 2: layer-0 LIF scan -> padded bitpacked S0 (unrolled x8) ======
__global__ void lif0(const float* __restrict__ I0T, uint32_t* __restrict__ S0P) {
#pragma clang fp contract(off)
    const int n = blockIdx.x * 64 + threadIdx.x;   // 0..4095
    uint32_t* rowp = S0P + n * S0W;
    rowp[0] = 0u;
    rowp[20] = 0u; rowp[21] = 0u; rowp[22] = 0u; rowp[23] = 0u;
    float v = 0.0f;
    uint32_t word = 0;
    int t = 0;
    for (; t + 8 <= T_STEPS; t += 8) {
        float I[8];
#pragma unroll
        for (int u = 0; u < 8; ++u) I[u] = I0T[(size_t)(t + u) * N0 + n];
#pragma unroll
        for (int u = 0; u < 8; ++u) {
            const int tt = t + u;
            float a = v * 0.9f;        // separate rounding (match jnp)
            v = a + I[u];
            if (v >= 1.0f) { word |= (1u << (tt & 31)); v = 0.0f; }
            if ((tt & 31) == 31) { rowp[1 + (tt >> 5)] = word; word = 0; }
        }
    }
    for (; t < T_STEPS; ++t) {
        float I = I0T[(size_t)t * N0 + n];
        float a = v * 0.9f;
        v = a + I;
        if (v >= 1.0f) { word |= (1u << (t & 31)); v = 0.0f; }
        if ((t & 31) == 31) { rowp[1 + (t >> 5)] = word; word = 0; }
    }
    rowp[1 + (T_STEPS >> 5)] = word;
}

// ====== Kernel 3: fused gather + layer-1 LIF + S1 output ======
// Thread owns 5 CONSECUTIVE t (t5 = 5*tid, tid<120): the 5 needed bits live
// in a 2-word window -> 2 dword loads + one 64-bit shift (was 5 strided
// loads). fma form: a += (double)bit * w (bit-exact).
__global__ __launch_bounds__(128) void gather_lif1(const float* __restrict__ W1,
                                                   const int* __restrict__ delays,
                                                   const uint32_t* __restrict__ S0P,
                                                   float* __restrict__ out) {
#pragma clang fp contract(off)
    __shared__ double  wl[N0];      // 32 KB
    __shared__ uint8_t dl[N0];      // 4 KB
    __shared__ float   i1row[T_RAW];
    const int j   = blockIdx.x;
    const int tid = threadIdx.x;
    for (int q = tid; q < N0 / 4; q += 128) {
        const float4 w4 = *reinterpret_cast<const float4*>(&W1[(size_t)j * N0 + 4 * q]);
        wl[4 * q + 0] = (double)w4.x; wl[4 * q + 1] = (double)w4.y;
        wl[4 * q + 2] = (double)w4.z; wl[4 * q + 3] = (double)w4.w;
        const int4 dv = *reinterpret_cast<const int4*>(&delays[(size_t)j * N0 + 4 * q]);
        dl[4 * q + 0] = (uint8_t)dv.x; dl[4 * q + 1] = (uint8_t)dv.y;
        dl[4 * q + 2] = (uint8_t)dv.z; dl[4 * q + 3] = (uint8_t)dv.w;
    }
    __syncthreads();
    const int t5 = 5 * tid;                     // 0,5,...,595 (tid<120)
    double a0 = 0.0, a1 = 0.0, a2 = 0.0, a3 = 0.0, a4 = 0.0;
    const uint32_t* rp0 = S0P;
#pragma unroll 2
    for (int i = 0; i < N0; ++i) {
        const int s0  = t5 - (int)dl[i];        // [-15, 595]
        const double w = wl[i];
        const int widx = (s0 >> 5) + 1;         // 0..19 (tid<120); <=20 idle lanes
        const int sh   = s0 & 31;
        const uint32_t lo = rp0[widx];
        const uint32_t hi = rp0[widx + 1];
        const uint32_t w5 = (uint32_t)(((((uint64_t)hi) << 32) | lo) >> sh);
        a0 = fma((double)( w5       & 1u), w, a0);
        a1 = fma((double)((w5 >> 1) & 1u), w, a1);
        a2 = fma((double)((w5 >> 2) & 1u), w, a2);
        a3 = fma((double)((w5 >> 3) & 1u), w, a3);
        a4 = fma((double)((w5 >> 4) & 1u), w, a4);
        rp0 += S0W;
    }
    if (tid < 120) {
        i1row[t5 + 0] = (float)a0;
        i1row[t5 + 1] = (float)a1;
        i1row[t5 + 2] = (float)a2;
        i1row[t5 + 3] = (float)a3;
        i1row[t5 + 4] = (float)a4;              // t=599 slot unused, harmless
    }
    __syncthreads();
    if (tid == 0) {
        float* o = out + (size_t)N0 * T_STEPS + (size_t)j * T_STEPS;
        float v = 0.0f;
        for (int t = 0; t < T_STEPS; ++t) {
            float a = v * 0.9f;                 // separate rounding (match jnp)
            v = a + i1row[t];
            float s = 0.0f;
            if (v >= 1.0f) { s = 1.0f; v = 0.0f; }
            o[t] = s;
        }
    }
}

// ====== Kernel 4: expand S0 bits -> fp32 output (S0.T) ======
__global__ void expand_out(const uint32_t* __restrict__ S0P,
                           float* __restrict__ out) {
    const int t = blockIdx.x * 256 + threadIdx.x;
    if (t >= T_STEPS) return;
    const int row = blockIdx.y;
    uint32_t b = (S0P[row * S0W + 1 + (t >> 5)] >> (t & 31)) & 1u;
    out[(size_t)row * T_STEPS + t] = (float)b;
}

extern "C" void kernel_launch(void* const* d_in, const int* in_sizes, int n_in,
                              void* d_out, int out_size, void* d_ws, size_t ws_size,
                              hipStream_t stream) {
    const float* stim   = (const float*)d_in[0];   // 128*128*600
    const float* W0     = (const float*)d_in[1];   // 4096*16384
    const float* W1     = (const float*)d_in[2];   // 1024*4096
    const int*   delays = (const int*)d_in[3];     // 1024*4096

    char* ws = (char*)d_ws;
    float*    I0T  = (float*)(ws + OFF_I0T);
    uint32_t* S0b  = (uint32_t*)(ws + OFF_S0B);
    float*    Xt   = (float*)(ws + OFF_XT);
    float*    out  = (float*)d_out;

    if (ws_size >= OFF_XT + SZ_XT) {
        hipLaunchKernelGGL(transpose_stim, dim3(10, 256), dim3(256), 0, stream, stim, Xt);
        hipLaunchKernelGGL(gemm_i0_xt,     dim3(1280),    dim3(256), 0, stream, W0, Xt, I0T);
    } else {
        hipLaunchKernelGGL(gemm_i0_fb,     dim3(1280),    dim3(256), 0, stream, W0, stim, I0T);
    }
    hipLaunchKernelGGL(lif0,        dim3(64),    dim3(64),  0, stream, I0T, S0b);
    hipLaunchKernelGGL(gather_lif1, dim3(1024),  dim3(128), 0, stream, W1, delays, S0b, out);
    hipLaunchKernelGGL(expand_out,  dim3(3, N0), dim3(256), 0, stream, S0b, out);
}

// Round 12
// 2204.809 us; speedup vs baseline: 1.0757x; 1.0034x over previous
//
#include <hip/hip_runtime.h>
#include <stdint.h>
#include <math.h>

#define T_STEPS 599   // T-1 scan steps (x[1:])
#define T_RAW   600
#define NIN     16384
#define N0      4096
#define N1      1024
#define S0W     24    // padded words per S0 row: [pad0][19 spike words][4 zero]
#define TAUP    640   // padded tau extent of Xt

typedef double d4 __attribute__((ext_vector_type(4)));

// ---- workspace layout (bytes) ----
static const size_t OFF_I0T = 0;
static const size_t SZ_I0T  = (size_t)T_STEPS * N0 * 4;      // 9,814,016
static const size_t OFF_S0B = OFF_I0T + SZ_I0T;
static const size_t SZ_S0B  = (size_t)N0 * S0W * 4;          // 393,216
static const size_t OFF_XT  = OFF_S0B + SZ_S0B;
static const size_t SZ_XT   = (size_t)TAUP * NIN * 4;        // 41,943,040 (~52.3 MB total)

// ====== Kernel 0: transpose stim[k][tau] -> Xt[tau][k] (bakes +1 shift, zero pad) ======
__global__ __launch_bounds__(256) void transpose_stim(const float* __restrict__ stim,
                                                      float* __restrict__ Xt) {
    __shared__ float T[64][65];
    const int tau0 = blockIdx.x * 64;   // 0..576 (10 blocks)
    const int k0   = blockIdx.y * 64;   // 0..16320 (256 blocks)
    const int tid  = threadIdx.x;
    const int kk = tid >> 2;
    const int tb = tid & 3;
#pragma unroll
    for (int q = 0; q < 16; ++q) {
        const int tl = tb + 4 * q;
        const int tg = tau0 + tl;                 // Xt tau index
        float v = 0.0f;
        if (tg <= T_STEPS - 1) v = stim[(size_t)(k0 + kk) * T_RAW + tg + 1];
        T[kk][tl] = v;
    }
    __syncthreads();
    const int tt = tid >> 2;
    const int kq = (tid & 3) * 16;
#pragma unroll
    for (int j = 0; j < 4; ++j) {
        const int kl = kq + 4 * j;
        float4 o;
        o.x = T[kl + 0][tt]; o.y = T[kl + 1][tt];
        o.z = T[kl + 2][tt]; o.w = T[kl + 3][tt];
        *reinterpret_cast<float4*>(&Xt[(size_t)(tau0 + tt) * NIN + k0 + kl]) = o;
    }
}

// ====== Kernel 1 (fast): I0 = W0 @ X, fp64 MFMA, all-b128 LDS reads ======
// R11 structure EXACTLY, with LDS shrunk below 32KB for 5 blocks/CU:
// A pad 44 -> 36 (rows 144B, b128 quad id = (r15+c)%8 -> uniform, optimal),
// B keeps pad 44. Total 2*(4608+11264) = 31744 B -> 5 resident blocks/CU ->
// grid 1280 = exactly 5/CU, single tranche (was 4/CU + 256-block straggler).
__global__ __launch_bounds__(256, 5) void gemm_i0_xt(const float* __restrict__ W0,
                                                     const float* __restrict__ Xt,
                                                     float* __restrict__ I0T) {
    __shared__ __align__(16) char smem[31744];
    float* As0 = (float*)(smem);             // 32*36*4 = 4608
    float* As1 = (float*)(smem + 4608);
    float* Bt0 = (float*)(smem + 9216);      // 64*44*4 = 11264
    float* Bt1 = (float*)(smem + 20480);
    const int tid  = threadIdx.x;
    const int lane = tid & 63;
    const int wid  = tid >> 6;
    const int kbase = 16 * (wid >> 1);       // k half: 0 or 16
    const int coff  = 32 * (wid & 1);        // tau half: 0 or 32
    const int flat = blockIdx.x;
    const int idx  = (flat & 7) * 160 + (flat >> 3);   // XCD swizzle (1280%8==0)
    const int n0   = (idx / 10) * 32;
    const int tau0 = (idx % 10) * 64;
    const int r15  = lane & 15;
    const int c    = lane >> 4;              // MFMA slot 0..3

    // ---- probe the C/D layout of v_mfma_f64_16x16x4f64 (proven R3) ----
    d4 zero = {0.0, 0.0, 0.0, 0.0};
    const double ap1 = (c == 0) ? 1.0 : 0.0;
    const double bp1 = (c == 0) ? (double)r15 : 0.0;
    d4 pcol = __builtin_amdgcn_mfma_f64_16x16x4f64(ap1, bp1, zero, 0, 0, 0);
    const double ap2 = (c == 0) ? (double)r15 : 0.0;
    const double bp2 = (c == 0) ? 1.0 : 0.0;
    d4 prow = __builtin_amdgcn_mfma_f64_16x16x4f64(ap2, bp2, zero, 0, 0, 0);
    int rowr[4], colr[4];
#pragma unroll
    for (int r = 0; r < 4; ++r) {
        int cc = (int)pcol[r]; cc = cc < 0 ? 0 : (cc > 15 ? 15 : cc);
        int rw = (int)prow[r]; rw = rw < 0 ? 0 : (rw > 15 ? 15 : rw);
        colr[r] = cc; rowr[r] = rw;
    }

    // ---- staging maps ----
    const int ar   = tid >> 3;           // A row 0..31
    const int ac4  = (tid & 7) * 4;      // A k-col (float4)
    const int btau = tid >> 2;           // B tau row 0..63
    const int bk8  = (tid & 3) * 8;      // B k-col base (2 float4)

    const float* aP  = W0 + (size_t)(n0 + ar) * NIN + ac4;
    const float* xP  = Xt + (size_t)(tau0 + btau) * NIN + bk8;

    float4 aR, bR0, bR1;                 // named staging regs (NO arrays)

#define XLOAD()                                                           \
    aR  = *reinterpret_cast<const float4*>(aP);                           \
    bR0 = *reinterpret_cast<const float4*>(xP);                           \
    bR1 = *reinterpret_cast<const float4*>(xP + 4);                       \
    aP += 32; xP += 32;

#define XSTAGE(AS, BS)                                                    \
    *reinterpret_cast<float4*>(&AS[ar * 36 + ac4]) = aR;                  \
    *reinterpret_cast<float4*>(&BS[btau * 44 + bk8]) = bR0;               \
    *reinterpret_cast<float4*>(&BS[btau * 44 + bk8 + 4]) = bR1;

    // 4 accumulators: c{p}{m}: rows p*16+, taus coff + m*16+
    d4 c00 = {0,0,0,0}, c01 = {0,0,0,0};
    d4 c10 = {0,0,0,0}, c11 = {0,0,0,0};

#define XMFMA(AS, BS)                                                     \
    {                                                                     \
        __builtin_amdgcn_s_setprio(1);                                    \
        const float4 a0f = *reinterpret_cast<const float4*>(&AS[r15 * 36 + kbase + 4 * c]);        \
        const float4 a1f = *reinterpret_cast<const float4*>(&AS[(16 + r15) * 36 + kbase + 4 * c]); \
        const float4 b0f = *reinterpret_cast<const float4*>(&BS[(coff + r15) * 44 + kbase + 4 * c]);      \
        const float4 b1f = *reinterpret_cast<const float4*>(&BS[(coff + 16 + r15) * 44 + kbase + 4 * c]); \
        c00 = __builtin_amdgcn_mfma_f64_16x16x4f64((double)a0f.x, (double)b0f.x, c00, 0, 0, 0);    \
        c01 = __builtin_amdgcn_mfma_f64_16x16x4f64((double)a0f.x, (double)b1f.x, c01, 0, 0, 0);    \
        c10 = __builtin_amdgcn_mfma_f64_16x16x4f64((double)a1f.x, (double)b0f.x, c10, 0, 0, 0);    \
        c11 = __builtin_amdgcn_mfma_f64_16x16x4f64((double)a1f.x, (double)b1f.x, c11, 0, 0, 0);    \
        c00 = __builtin_amdgcn_mfma_f64_16x16x4f64((double)a0f.y, (double)b0f.y, c00, 0, 0, 0);    \
        c01 = __builtin_amdgcn_mfma_f64_16x16x4f64((double)a0f.y, (double)b1f.y, c01, 0, 0, 0);    \
        c10 = __builtin_amdgcn_mfma_f64_16x16x4f64((double)a1f.y, (double)b0f.y, c10, 0, 0, 0);    \
        c11 = __builtin_amdgcn_mfma_f64_16x16x4f64((double)a1f.y, (double)b1f.y, c11, 0, 0, 0);    \
        c00 = __builtin_amdgcn_mfma_f64_16x16x4f64((double)a0f.z, (double)b0f.z, c00, 0, 0, 0);    \
        c01 = __builtin_amdgcn_mfma_f64_16x16x4f64((double)a0f.z, (double)b1f.z, c01, 0, 0, 0);    \
        c10 = __builtin_amdgcn_mfma_f64_16x16x4f64((double)a1f.z, (double)b0f.z, c10, 0, 0, 0);    \
        c11 = __builtin_amdgcn_mfma_f64_16x16x4f64((double)a1f.z, (double)b1f.z, c11, 0, 0, 0);    \
        c00 = __builtin_amdgcn_mfma_f64_16x16x4f64((double)a0f.w, (double)b0f.w, c00, 0, 0, 0);    \
        c01 = __builtin_amdgcn_mfma_f64_16x16x4f64((double)a0f.w, (double)b1f.w, c01, 0, 0, 0);    \
        c10 = __builtin_amdgcn_mfma_f64_16x16x4f64((double)a1f.w, (double)b0f.w, c10, 0, 0, 0);    \
        c11 = __builtin_amdgcn_mfma_f64_16x16x4f64((double)a1f.w, (double)b1f.w, c11, 0, 0, 0);    \
        __builtin_amdgcn_s_setprio(0);                                    \
    }

    XLOAD();                             // prologue: chunk 0
    for (int chp = 0; chp < 256; ++chp) {
        XSTAGE(As0, Bt0);
        __syncthreads();
        XLOAD();
        XMFMA(As0, Bt0);
        XSTAGE(As1, Bt1);
        __syncthreads();
        if (chp + 1 < 256) { XLOAD(); }
        XMFMA(As1, Bt1);
    }
#undef XLOAD
#undef XSTAGE
#undef XMFMA

    // ---- cross-wave reduction over kh: Cred[col][row] aliases staging LDS ----
    __syncthreads();
    double* Cred = (double*)smem;        // 64*32*8 = 16384 <= 31744

#define CRED_OP(OP)                                                       \
    _Pragma("unroll")                                                     \
    for (int r = 0; r < 4; ++r) {                                         \
        const int ro = rowr[r], co = coff + colr[r];                      \
        Cred[(co     ) * 32 + ro     ] OP c00[r];                         \
        Cred[(co + 16) * 32 + ro     ] OP c01[r];                         \
        Cred[(co     ) * 32 + ro + 16] OP c10[r];                         \
        Cred[(co + 16) * 32 + ro + 16] OP c11[r];                         \
    }
    if (wid < 2)  { CRED_OP(=) }
    __syncthreads();
    if (wid >= 2) { CRED_OP(+=) }
    __syncthreads();
#undef CRED_OP

    const int scol = tid >> 2;
    const int srow = (tid & 3) * 8;
    const int tcol = tau0 + scol;
    if (tcol < T_STEPS) {
        const double* cp = &Cred[scol * 32 + srow];
        float4 o0, o1;
        o0.x = (float)cp[0]; o0.y = (float)cp[1]; o0.z = (float)cp[2]; o0.w = (float)cp[3];
        o1.x = (float)cp[4]; o1.y = (float)cp[5]; o1.z = (float)cp[6]; o1.w = (float)cp[7];
        float* op = &I0T[(size_t)tcol * N0 + n0 + srow];
        *reinterpret_cast<float4*>(op)     = o0;
        *reinterpret_cast<float4*>(op + 4) = o1;
    }
}

// ====== Kernel 1 (fallback, R9-exact): used only if ws too small for Xt ======
__global__ __launch_bounds__(256, 5) void gemm_i0_fb(const float* __restrict__ W0,
                                                     const float* __restrict__ stim,
                                                     float* __restrict__ I0T) {
    __shared__ __align__(16) char smem[27904];
    float* As0 = (float*)(smem);
    float* As1 = (float*)(smem + 4736);
    float* Bs0 = (float*)(smem + 9472);
    float* Bs1 = (float*)(smem + 18688);
    const int tid  = threadIdx.x;
    const int lane = tid & 63;
    const int wid  = tid >> 6;
    const int kbase = 16 * (wid >> 1);
    const int coff  = 32 * (wid & 1);
    const int flat = blockIdx.x;
    const int idx  = (flat & 7) * 160 + (flat >> 3);
    const int n0   = (idx / 10) * 32;
    const int tau0 = (idx % 10) * 64;
    const int r15  = lane & 15;
    const int c    = lane >> 4;
    d4 zero = {0.0, 0.0, 0.0, 0.0};
    const double ap1 = (c == 0) ? 1.0 : 0.0;
    const double bp1 = (c == 0) ? (double)r15 : 0.0;
    d4 pcol = __builtin_amdgcn_mfma_f64_16x16x4f64(ap1, bp1, zero, 0, 0, 0);
    const double ap2 = (c == 0) ? (double)r15 : 0.0;
    const double bp2 = (c == 0) ? 1.0 : 0.0;
    d4 prow = __builtin_amdgcn_mfma_f64_16x16x4f64(ap2, bp2, zero, 0, 0, 0);
    int rowr[4], colr[4];
#pragma unroll
    for (int r = 0; r < 4; ++r) {
        int cc = (int)pcol[r]; cc = cc < 0 ? 0 : (cc > 15 ? 15 : cc);
        int rw = (int)prow[r]; rw = rw < 0 ? 0 : (rw > 15 ? 15 : rw);
        colr[r] = cc; rowr[r] = rw;
    }
    const int ar  = tid >> 3;
    const int ac4 = (tid & 7) * 4;
    const int br  = tid >> 4;
    const int bc4 = (tid & 15) * 4;
    const int t0g = tau0 + bc4;
    const bool fastB = (tau0 + 68) <= T_RAW;
    const float* aP  = W0 + (size_t)(n0 + ar) * NIN + ac4;
    const float* bP0 = stim + (size_t)br * T_RAW + t0g;
    const float* bP1 = stim + (size_t)(br + 16) * T_RAW + t0g;
    float4 aR, bRa, bRb;
#define FLOAD()                                                           \
    aR = *reinterpret_cast<const float4*>(aP);                            \
    if (fastB) {                                                          \
        float4 f0 = *reinterpret_cast<const float4*>(bP0);                \
        float  e0 = bP0[4];                                               \
        bRa.x = f0.y; bRa.y = f0.z; bRa.z = f0.w; bRa.w = e0;             \
        float4 f1 = *reinterpret_cast<const float4*>(bP1);                \
        float  e1 = bP1[4];                                               \
        bRb.x = f1.y; bRb.y = f1.z; bRb.z = f1.w; bRb.w = e1;             \
    } else {                                                              \
        bRa.x = (t0g + 0 < T_STEPS) ? bP0[1] : 0.0f;                      \
        bRa.y = (t0g + 1 < T_STEPS) ? bP0[2] : 0.0f;                      \
        bRa.z = (t0g + 2 < T_STEPS) ? bP0[3] : 0.0f;                      \
        bRa.w = (t0g + 3 < T_STEPS) ? bP0[4] : 0.0f;                      \
        bRb.x = (t0g + 0 < T_STEPS) ? bP1[1] : 0.0f;                      \
        bRb.y = (t0g + 1 < T_STEPS) ? bP1[2] : 0.0f;                      \
        bRb.z = (t0g + 2 < T_STEPS) ? bP1[3] : 0.0f;                      \
        bRb.w = (t0g + 3 < T_STEPS) ? bP1[4] : 0.0f;                      \
    }                                                                     \
    aP += 32; bP0 += 32 * T_RAW; bP1 += 32 * T_RAW;
#define FSTAGE(AS, BS)                                                    \
    *reinterpret_cast<float4*>(&AS[ar * 37 + ac4]) = aR;                  \
    *reinterpret_cast<float4*>(&BS[br * 72 + bc4]) = bRa;                 \
    *reinterpret_cast<float4*>(&BS[(br + 16) * 72 + bc4]) = bRb;
#define FKSTEP(AS, BS, KK)                                                \
    {                                                                     \
        const double a0 = (double)AS[r15 * 37 + (KK)];                    \
        const double a1 = (double)AS[(16 + r15) * 37 + (KK)];             \
        const double b0 = (double)BS[(KK) * 72 + coff + r15];             \
        const double b1 = (double)BS[(KK) * 72 + coff + 16 + r15];        \
        c00 = __builtin_amdgcn_mfma_f64_16x16x4f64(a0, b0, c00, 0, 0, 0); \
        c01 = __builtin_amdgcn_mfma_f64_16x16x4f64(a0, b1, c01, 0, 0, 0); \
        c10 = __builtin_amdgcn_mfma_f64_16x16x4f64(a1, b0, c10, 0, 0, 0); \
        c11 = __builtin_amdgcn_mfma_f64_16x16x4f64(a1, b1, c11, 0, 0, 0); \
    }
#define FMFMA(AS, BS)                                                     \
    __builtin_amdgcn_s_setprio(1);                                        \
    FKSTEP(AS, BS, kbase + c);                                            \
    FKSTEP(AS, BS, kbase + 4 + c);                                        \
    FKSTEP(AS, BS, kbase + 8 + c);                                        \
    FKSTEP(AS, BS, kbase + 12 + c);                                       \
    __builtin_amdgcn_s_setprio(0);
    d4 c00 = {0,0,0,0}, c01 = {0,0,0,0};
    d4 c10 = {0,0,0,0}, c11 = {0,0,0,0};
    FLOAD();
    for (int chp = 0; chp < 256; ++chp) {
        FSTAGE(As0, Bs0);
        __syncthreads();
        FLOAD();
        FMFMA(As0, Bs0);
        FSTAGE(As1, Bs1);
        __syncthreads();
        if (chp + 1 < 256) { FLOAD(); }
        FMFMA(As1, Bs1);
    }
#undef FLOAD
#undef FSTAGE
#undef FKSTEP
#undef FMFMA
    __syncthreads();
    double* Cred = (double*)smem;
#define CRED_OP(OP)                                                       \
    _Pragma("unroll")                                                     \
    for (int r = 0; r < 4; ++r) {                                         \
        const int ro = rowr[r], co = coff + colr[r];                      \
        Cred[(co     ) * 32 + ro     ] OP c00[r];                         \
        Cred[(co + 16) * 32 + ro     ] OP c01[r];                         \
        Cred[(co     ) * 32 + ro + 16] OP c10[r];                         \
        Cred[(co + 16) * 32 + ro + 16] OP c11[r];                         \
    }
    if (wid < 2)  { CRED_OP(=) }
    __syncthreads();
    if (wid >= 2) { CRED_OP(+=) }
    __syncthreads();
#undef CRED_OP
    const int scol = tid >> 2;
    const int srow = (tid & 3) * 8;
    const int tcol = tau0 + scol;
    if (tcol < T_STEPS) {
        const double* cp = &Cred[scol * 32 + srow];
        float4 o0, o1;
        o0.x = (float)cp[0]; o0.y = (float)cp[1]; o0.z = (float)cp[2]; o0.w = (float)cp[3];
        o1.x = (float)cp[4]; o1.y = (float)cp[5]; o1.z = (float)cp[6]; o1.w = (float)cp[7];
        float* op = &I0T[(size_t)tcol * N0 + n0 + srow];
        *reinterpret_cast<float4*>(op)     = o0;
        *reinterpret_cast<float4*>(op + 4) = o1;
    }
}

// ====== Kernel 2: layer-0 LIF scan -> padded bitpacked S0 (unrolled x8) ======
__global__ void lif0(const float* __restrict__ I0T, uint32_t* __restrict__ S0P) {
#pragma clang fp contract(off)
    const int n = blockIdx.x * 64 + threadIdx.x;   // 0..4095
    uint32_t* rowp = S0P + n * S0W;
    rowp[0] = 0u;
    rowp[20] = 0u; rowp[21] = 0u; rowp[22] = 0u; rowp[23] = 0u;
    float v = 0.0f;
    uint32_t word = 0;
    int t = 0;
    for (; t + 8 <= T_STEPS; t += 8) {
        float I[8];
#pragma unroll
        for (int u = 0; u < 8; ++u) I[u] = I0T[(size_t)(t + u) * N0 + n];
#pragma unroll
        for (int u = 0; u < 8; ++u) {
            const int tt = t + u;
            float a = v * 0.9f;        // separate rounding (match jnp)
            v = a + I[u];
            if (v >= 1.0f) { word |= (1u << (tt & 31)); v = 0.0f; }
            if ((tt & 31) == 31) { rowp[1 + (tt >> 5)] = word; word = 0; }
        }
    }
    for (; t < T_STEPS; ++t) {
        float I = I0T[(size_t)t * N0 + n];
        float a = v * 0.9f;
        v = a + I;
        if (v >= 1.0f) { word |= (1u << (t & 31)); v = 0.0f; }
        if ((t & 31) == 31) { rowp[1 + (t >> 5)] = word; word = 0; }
    }
    rowp[1 + (T_STEPS >> 5)] = word;
}

// ====== Kernel 3: fused gather + layer-1 LIF + S1 output ======
__global__ __launch_bounds__(128) void gather_lif1(const float* __restrict__ W1,
                                                   const int* __restrict__ delays,
                                                   const uint32_t* __restrict__ S0P,
                                                   float* __restrict__ out) {
#pragma clang fp contract(off)
    __shared__ double  wl[N0];      // 32 KB
    __shared__ uint8_t dl[N0];      // 4 KB
    __shared__ float   i1row[T_RAW];
    const int j   = blockIdx.x;
    const int tid = threadIdx.x;
    for (int q = tid; q < N0 / 4; q += 128) {
        const float4 w4 = *reinterpret_cast<const float4*>(&W1[(size_t)j * N0 + 4 * q]);
        wl[4 * q + 0] = (double)w4.x; wl[4 * q + 1] = (double)w4.y;
        wl[4 * q + 2] = (double)w4.z; wl[4 * q + 3] = (double)w4.w;
        const int4 dv = *reinterpret_cast<const int4*>(&delays[(size_t)j * N0 + 4 * q]);
        dl[4 * q + 0] = (uint8_t)dv.x; dl[4 * q + 1] = (uint8_t)dv.y;
        dl[4 * q + 2] = (uint8_t)dv.z; dl[4 * q + 3] = (uint8_t)dv.w;
    }
    __syncthreads();
    const int t5 = 5 * tid;                     // 0,5,...,595 (tid<120)
    double a0 = 0.0, a1 = 0.0, a2 = 0.0, a3 = 0.0, a4 = 0.0;
    const uint32_t* rp0 = S0P + 1;              // +1 word bias folds the pad offset
#pragma unroll 2
    for (int i = 0; i < N0; ++i) {
        const int s0  = t5 - (int)dl[i];        // [-15, 595]
        const double w = wl[i];
        const int widx = (s0 >> 5);             // -1..18; rp0 bias makes it valid
        const int sh   = s0 & 31;
        const uint32_t lo = rp0[widx];
        const uint32_t hi = rp0[widx + 1];
        const uint32_t w5 = (uint32_t)(((((uint64_t)hi) << 32) | lo) >> sh);
        a0 = fma((double)( w5       & 1u), w, a0);
        a1 = fma((double)((w5 >> 1) & 1u), w, a1);
        a2 = fma((double)((w5 >> 2) & 1u), w, a2);
        a3 = fma((double)((w5 >> 3) & 1u), w, a3);
        a4 = fma((double)((w5 >> 4) & 1u), w, a4);
        rp0 += S0W;
    }
    if (tid < 120) {
        i1row[t5 + 0] = (float)a0;
        i1row[t5 + 1] = (float)a1;
        i1row[t5 + 2] = (float)a2;
        i1row[t5 + 3] = (float)a3;
        i1row[t5 + 4] = (float)a4;              // t=599 slot unused, harmless
    }
    __syncthreads();
    if (tid == 0) {
        float* o = out + (size_t)N0 * T_STEPS + (size_t)j * T_STEPS;
        float v = 0.0f;
        for (int t = 0; t < T_STEPS; ++t) {
            float a = v * 0.9f;                 // separate rounding (match jnp)
            v = a + i1row[t];
            float s = 0.0f;
            if (v >= 1.0f) { s = 1.0f; v = 0.0f; }
            o[t] = s;
        }
    }
}

// ====== Kernel 4: expand S0 bits -> fp32 output (S0.T) ======
__global__ void expand_out(const uint32_t* __restrict__ S0P,
                           float* __restrict__ out) {
    const int t = blockIdx.x * 256 + threadIdx.x;
    if (t >= T_STEPS) return;
    const int row = blockIdx.y;
    uint32_t b = (S0P[row * S0W + 1 + (t >> 5)] >> (t & 31)) & 1u;
    out[(size_t)row * T_STEPS + t] = (float)b;
}

extern "C" void kernel_launch(void* const* d_in, const int* in_sizes, int n_in,
                              void* d_out, int out_size, void* d_ws, size_t ws_size,
                              hipStream_t stream) {
    const float* stim   = (const float*)d_in[0];   // 128*128*600
    const float* W0     = (const float*)d_in[1];   // 4096*16384
    const float* W1     = (const float*)d_in[2];   // 1024*4096
    const int*   delays = (const int*)d_in[3];     // 1024*4096

    char* ws = (char*)d_ws;
    float*    I0T  = (float*)(ws + OFF_I0T);
    uint32_t* S0b  = (uint32_t*)(ws + OFF_S0B);
    float*    Xt   = (float*)(ws + OFF_XT);
    float*    out  = (float*)d_out;

    if (ws_size >= OFF_XT + SZ_XT) {
        hipLaunchKernelGGL(transpose_stim, dim3(10, 256), dim3(256), 0, stream, stim, Xt);
        hipLaunchKernelGGL(gemm_i0_xt,     dim3(1280),    dim3(256), 0, stream, W0, Xt, I0T);
    } else {
        hipLaunchKernelGGL(gemm_i0_fb,     dim3(1280),    dim3(256), 0, stream, W0, stim, I0T);
    }
    hipLaunchKernelGGL(lif0,        dim3(64),    dim3(64),  0, stream, I0T, S0b);
    hipLaunchKernelGGL(gather_lif1, dim3(1024),  dim3(128), 0, stream, W1, delays, S0b, out);
    hipLaunchKernelGGL(expand_out,  dim3(3, N0), dim3(256), 0, stream, S0b, out);
}

// Round 13
// 1860.650 us; speedup vs baseline: 1.2747x; 1.1850x over previous
//
#include <hip/hip_runtime.h>
#include <stdint.h>
#include <math.h>

#define T_STEPS 599   // T-1 scan steps (x[1:])
#define T_RAW   600
#define NIN     16384
#define N0      4096
#define N1      1024
#define S0W     24    // padded words per S0 row: [pad0][19 spike words][4 zero]
#define TAUP    640   // padded tau extent of Xt

typedef double d4 __attribute__((ext_vector_type(4)));

// ---- workspace layout (bytes) ----
// I0T region is reused as the gather partial buffer after lif0x consumes it:
// part[2048][599] doubles = 9,814,016 B == SZ_I0T exactly.
static const size_t OFF_I0T = 0;
static const size_t SZ_I0T  = (size_t)T_STEPS * N0 * 4;      // 9,814,016
static const size_t OFF_S0B = OFF_I0T + SZ_I0T;
static const size_t SZ_S0B  = (size_t)N0 * S0W * 4;          // 393,216
static const size_t OFF_XT  = OFF_S0B + SZ_S0B;
static const size_t SZ_XT   = (size_t)TAUP * NIN * 4;        // 41,943,040 (~52.3 MB total)

// ====== Kernel 0: transpose stim[k][tau] -> Xt[tau][k] (bakes +1 shift, zero pad) ======
__global__ __launch_bounds__(256) void transpose_stim(const float* __restrict__ stim,
                                                      float* __restrict__ Xt) {
    __shared__ float T[64][65];
    const int tau0 = blockIdx.x * 64;   // 0..576 (10 blocks)
    const int k0   = blockIdx.y * 64;   // 0..16320 (256 blocks)
    const int tid  = threadIdx.x;
    const int kk = tid >> 2;
    const int tb = tid & 3;
#pragma unroll
    for (int q = 0; q < 16; ++q) {
        const int tl = tb + 4 * q;
        const int tg = tau0 + tl;                 // Xt tau index
        float v = 0.0f;
        if (tg <= T_STEPS - 1) v = stim[(size_t)(k0 + kk) * T_RAW + tg + 1];
        T[kk][tl] = v;
    }
    __syncthreads();
    const int tt = tid >> 2;
    const int kq = (tid & 3) * 16;
#pragma unroll
    for (int j = 0; j < 4; ++j) {
        const int kl = kq + 4 * j;
        float4 o;
        o.x = T[kl + 0][tt]; o.y = T[kl + 1][tt];
        o.z = T[kl + 2][tt]; o.w = T[kl + 3][tt];
        *reinterpret_cast<float4*>(&Xt[(size_t)(tau0 + tt) * NIN + k0 + kl]) = o;
    }
}

// ====== Kernel 1 (fast): I0 = W0 @ X, fp64 MFMA, all-b128 LDS reads ======
// R12-exact (proven 1495us @ MfmaUtil 78%).
__global__ __launch_bounds__(256, 5) void gemm_i0_xt(const float* __restrict__ W0,
                                                     const float* __restrict__ Xt,
                                                     float* __restrict__ I0T) {
    __shared__ __align__(16) char smem[31744];
    float* As0 = (float*)(smem);             // 32*36*4 = 4608
    float* As1 = (float*)(smem + 4608);
    float* Bt0 = (float*)(smem + 9216);      // 64*44*4 = 11264
    float* Bt1 = (float*)(smem + 20480);
    const int tid  = threadIdx.x;
    const int lane = tid & 63;
    const int wid  = tid >> 6;
    const int kbase = 16 * (wid >> 1);       // k half: 0 or 16
    const int coff  = 32 * (wid & 1);        // tau half: 0 or 32
    const int flat = blockIdx.x;
    const int idx  = (flat & 7) * 160 + (flat >> 3);   // XCD swizzle (1280%8==0)
    const int n0   = (idx / 10) * 32;
    const int tau0 = (idx % 10) * 64;
    const int r15  = lane & 15;
    const int c    = lane >> 4;              // MFMA slot 0..3

    // ---- probe the C/D layout of v_mfma_f64_16x16x4f64 (proven R3) ----
    d4 zero = {0.0, 0.0, 0.0, 0.0};
    const double ap1 = (c == 0) ? 1.0 : 0.0;
    const double bp1 = (c == 0) ? (double)r15 : 0.0;
    d4 pcol = __builtin_amdgcn_mfma_f64_16x16x4f64(ap1, bp1, zero, 0, 0, 0);
    const double ap2 = (c == 0) ? (double)r15 : 0.0;
    const double bp2 = (c == 0) ? 1.0 : 0.0;
    d4 prow = __builtin_amdgcn_mfma_f64_16x16x4f64(ap2, bp2, zero, 0, 0, 0);
    int rowr[4], colr[4];
#pragma unroll
    for (int r = 0; r < 4; ++r) {
        int cc = (int)pcol[r]; cc = cc < 0 ? 0 : (cc > 15 ? 15 : cc);
        int rw = (int)prow[r]; rw = rw < 0 ? 0 : (rw > 15 ? 15 : rw);
        colr[r] = cc; rowr[r] = rw;
    }

    // ---- staging maps ----
    const int ar   = tid >> 3;           // A row 0..31
    const int ac4  = (tid & 7) * 4;      // A k-col (float4)
    const int btau = tid >> 2;           // B tau row 0..63
    const int bk8  = (tid & 3) * 8;      // B k-col base (2 float4)

    const float* aP  = W0 + (size_t)(n0 + ar) * NIN + ac4;
    const float* xP  = Xt + (size_t)(tau0 + btau) * NIN + bk8;

    float4 aR, bR0, bR1;                 // named staging regs (NO arrays)

#define XLOAD()                                                           \
    aR  = *reinterpret_cast<const float4*>(aP);                           \
    bR0 = *reinterpret_cast<const float4*>(xP);                           \
    bR1 = *reinterpret_cast<const float4*>(xP + 4);                       \
    aP += 32; xP += 32;

#define XSTAGE(AS, BS)                                                    \
    *reinterpret_cast<float4*>(&AS[ar * 36 + ac4]) = aR;                  \
    *reinterpret_cast<float4*>(&BS[btau * 44 + bk8]) = bR0;               \
    *reinterpret_cast<float4*>(&BS[btau * 44 + bk8 + 4]) = bR1;

    d4 c00 = {0,0,0,0}, c01 = {0,0,0,0};
    d4 c10 = {0,0,0,0}, c11 = {0,0,0,0};

#define XMFMA(AS, BS)                                                     \
    {                                                                     \
        __builtin_amdgcn_s_setprio(1);                                    \
        const float4 a0f = *reinterpret_cast<const float4*>(&AS[r15 * 36 + kbase + 4 * c]);        \
        const float4 a1f = *reinterpret_cast<const float4*>(&AS[(16 + r15) * 36 + kbase + 4 * c]); \
        const float4 b0f = *reinterpret_cast<const float4*>(&BS[(coff + r15) * 44 + kbase + 4 * c]);      \
        const float4 b1f = *reinterpret_cast<const float4*>(&BS[(coff + 16 + r15) * 44 + kbase + 4 * c]); \
        c00 = __builtin_amdgcn_mfma_f64_16x16x4f64((double)a0f.x, (double)b0f.x, c00, 0, 0, 0);    \
        c01 = __builtin_amdgcn_mfma_f64_16x16x4f64((double)a0f.x, (double)b1f.x, c01, 0, 0, 0);    \
        c10 = __builtin_amdgcn_mfma_f64_16x16x4f64((double)a1f.x, (double)b0f.x, c10, 0, 0, 0);    \
        c11 = __builtin_amdgcn_mfma_f64_16x16x4f64((double)a1f.x, (double)b1f.x, c11, 0, 0, 0);    \
        c00 = __builtin_amdgcn_mfma_f64_16x16x4f64((double)a0f.y, (double)b0f.y, c00, 0, 0, 0);    \
        c01 = __builtin_amdgcn_mfma_f64_16x16x4f64((double)a0f.y, (double)b1f.y, c01, 0, 0, 0);    \
        c10 = __builtin_amdgcn_mfma_f64_16x16x4f64((double)a1f.y, (double)b0f.y, c10, 0, 0, 0);    \
        c11 = __builtin_amdgcn_mfma_f64_16x16x4f64((double)a1f.y, (double)b1f.y, c11, 0, 0, 0);    \
        c00 = __builtin_amdgcn_mfma_f64_16x16x4f64((double)a0f.z, (double)b0f.z, c00, 0, 0, 0);    \
        c01 = __builtin_amdgcn_mfma_f64_16x16x4f64((double)a0f.z, (double)b1f.z, c01, 0, 0, 0);    \
        c10 = __builtin_amdgcn_mfma_f64_16x16x4f64((double)a1f.z, (double)b0f.z, c10, 0, 0, 0);    \
        c11 = __builtin_amdgcn_mfma_f64_16x16x4f64((double)a1f.z, (double)b1f.z, c11, 0, 0, 0);    \
        c00 = __builtin_amdgcn_mfma_f64_16x16x4f64((double)a0f.w, (double)b0f.w, c00, 0, 0, 0);    \
        c01 = __builtin_amdgcn_mfma_f64_16x16x4f64((double)a0f.w, (double)b1f.w, c01, 0, 0, 0);    \
        c10 = __builtin_amdgcn_mfma_f64_16x16x4f64((double)a1f.w, (double)b0f.w, c10, 0, 0, 0);    \
        c11 = __builtin_amdgcn_mfma_f64_16x16x4f64((double)a1f.w, (double)b1f.w, c11, 0, 0, 0);    \
        __builtin_amdgcn_s_setprio(0);                                    \
    }

    XLOAD();                             // prologue: chunk 0
    for (int chp = 0; chp < 256; ++chp) {
        XSTAGE(As0, Bt0);
        __syncthreads();
        XLOAD();
        XMFMA(As0, Bt0);
        XSTAGE(As1, Bt1);
        __syncthreads();
        if (chp + 1 < 256) { XLOAD(); }
        XMFMA(As1, Bt1);
    }
#undef XLOAD
#undef XSTAGE
#undef XMFMA

    __syncthreads();
    double* Cred = (double*)smem;        // 64*32*8 = 16384 <= 31744

#define CRED_OP(OP)                                                       \
    _Pragma("unroll")                                                     \
    for (int r = 0; r < 4; ++r) {                                         \
        const int ro = rowr[r], co = coff + colr[r];                      \
        Cred[(co     ) * 32 + ro     ] OP c00[r];                         \
        Cred[(co + 16) * 32 + ro     ] OP c01[r];                         \
        Cred[(co     ) * 32 + ro + 16] OP c10[r];                         \
        Cred[(co + 16) * 32 + ro + 16] OP c11[r];                         \
    }
    if (wid < 2)  { CRED_OP(=) }
    __syncthreads();
    if (wid >= 2) { CRED_OP(+=) }
    __syncthreads();
#undef CRED_OP

    const int scol = tid >> 2;
    const int srow = (tid & 3) * 8;
    const int tcol = tau0 + scol;
    if (tcol < T_STEPS) {
        const double* cp = &Cred[scol * 32 + srow];
        float4 o0, o1;
        o0.x = (float)cp[0]; o0.y = (float)cp[1]; o0.z = (float)cp[2]; o0.w = (float)cp[3];
        o1.x = (float)cp[4]; o1.y = (float)cp[5]; o1.z = (float)cp[6]; o1.w = (float)cp[7];
        float* op = &I0T[(size_t)tcol * N0 + n0 + srow];
        *reinterpret_cast<float4*>(op)     = o0;
        *reinterpret_cast<float4*>(op + 4) = o1;
    }
}

// ====== Kernel 1 (fallback, R9-exact): used only if ws too small for Xt ======
__global__ __launch_bounds__(256, 5) void gemm_i0_fb(const float* __restrict__ W0,
                                                     const float* __restrict__ stim,
                                                     float* __restrict__ I0T) {
    __shared__ __align__(16) char smem[27904];
    float* As0 = (float*)(smem);
    float* As1 = (float*)(smem + 4736);
    float* Bs0 = (float*)(smem + 9472);
    float* Bs1 = (float*)(smem + 18688);
    const int tid  = threadIdx.x;
    const int lane = tid & 63;
    const int wid  = tid >> 6;
    const int kbase = 16 * (wid >> 1);
    const int coff  = 32 * (wid & 1);
    const int flat = blockIdx.x;
    const int idx  = (flat & 7) * 160 + (flat >> 3);
    const int n0   = (idx / 10) * 32;
    const int tau0 = (idx % 10) * 64;
    const int r15  = lane & 15;
    const int c    = lane >> 4;
    d4 zero = {0.0, 0.0, 0.0, 0.0};
    const double ap1 = (c == 0) ? 1.0 : 0.0;
    const double bp1 = (c == 0) ? (double)r15 : 0.0;
    d4 pcol = __builtin_amdgcn_mfma_f64_16x16x4f64(ap1, bp1, zero, 0, 0, 0);
    const double ap2 = (c == 0) ? (double)r15 : 0.0;
    const double bp2 = (c == 0) ? 1.0 : 0.0;
    d4 prow = __builtin_amdgcn_mfma_f64_16x16x4f64(ap2, bp2, zero, 0, 0, 0);
    int rowr[4], colr[4];
#pragma unroll
    for (int r = 0; r < 4; ++r) {
        int cc = (int)pcol[r]; cc = cc < 0 ? 0 : (cc > 15 ? 15 : cc);
        int rw = (int)prow[r]; rw = rw < 0 ? 0 : (rw > 15 ? 15 : rw);
        colr[r] = cc; rowr[r] = rw;
    }
    const int ar  = tid >> 3;
    const int ac4 = (tid & 7) * 4;
    const int br  = tid >> 4;
    const int bc4 = (tid & 15) * 4;
    const int t0g = tau0 + bc4;
    const bool fastB = (tau0 + 68) <= T_RAW;
    const float* aP  = W0 + (size_t)(n0 + ar) * NIN + ac4;
    const float* bP0 = stim + (size_t)br * T_RAW + t0g;
    const float* bP1 = stim + (size_t)(br + 16) * T_RAW + t0g;
    float4 aR, bRa, bRb;
#define FLOAD()                                                           \
    aR = *reinterpret_cast<const float4*>(aP);                            \
    if (fastB) {                                                          \
        float4 f0 = *reinterpret_cast<const float4*>(bP0);                \
        float  e0 = bP0[4];                                               \
        bRa.x = f0.y; bRa.y = f0.z; bRa.z = f0.w; bRa.w = e0;             \
        float4 f1 = *reinterpret_cast<const float4*>(bP1);                \
        float  e1 = bP1[4];                                               \
        bRb.x = f1.y; bRb.y = f1.z; bRb.z = f1.w; bRb.w = e1;             \
    } else {                                                              \
        bRa.x = (t0g + 0 < T_STEPS) ? bP0[1] : 0.0f;                      \
        bRa.y = (t0g + 1 < T_STEPS) ? bP0[2] : 0.0f;                      \
        bRa.z = (t0g + 2 < T_STEPS) ? bP0[3] : 0.0f;                      \
        bRa.w = (t0g + 3 < T_STEPS) ? bP0[4] : 0.0f;                      \
        bRb.x = (t0g + 0 < T_STEPS) ? bP1[1] : 0.0f;                      \
        bRb.y = (t0g + 1 < T_STEPS) ? bP1[2] : 0.0f;                      \
        bRb.z = (t0g + 2 < T_STEPS) ? bP1[3] : 0.0f;                      \
        bRb.w = (t0g + 3 < T_STEPS) ? bP1[4] : 0.0f;                      \
    }                                                                     \
    aP += 32; bP0 += 32 * T_RAW; bP1 += 32 * T_RAW;
#define FSTAGE(AS, BS)                                                    \
    *reinterpret_cast<float4*>(&AS[ar * 37 + ac4]) = aR;                  \
    *reinterpret_cast<float4*>(&BS[br * 72 + bc4]) = bRa;                 \
    *reinterpret_cast<float4*>(&BS[(br + 16) * 72 + bc4]) = bRb;
#define FKSTEP(AS, BS, KK)                                                \
    {                                                                     \
        const double a0 = (double)AS[r15 * 37 + (KK)];                    \
        const double a1 = (double)AS[(16 + r15) * 37 + (KK)];             \
        const double b0 = (double)BS[(KK) * 72 + coff + r15];             \
        const double b1 = (double)BS[(KK) * 72 + coff + 16 + r15];        \
        c00 = __builtin_amdgcn_mfma_f64_16x16x4f64(a0, b0, c00, 0, 0, 0); \
        c01 = __builtin_amdgcn_mfma_f64_16x16x4f64(a0, b1, c01, 0, 0, 0); \
        c10 = __builtin_amdgcn_mfma_f64_16x16x4f64(a1, b0, c10, 0, 0, 0); \
        c11 = __builtin_amdgcn_mfma_f64_16x16x4f64(a1, b1, c11, 0, 0, 0); \
    }
#define FMFMA(AS, BS)                                                     \
    __builtin_amdgcn_s_setprio(1);                                        \
    FKSTEP(AS, BS, kbase + c);                                            \
    FKSTEP(AS, BS, kbase + 4 + c);                                        \
    FKSTEP(AS, BS, kbase + 8 + c);                                        \
    FKSTEP(AS, BS, kbase + 12 + c);                                       \
    __builtin_amdgcn_s_setprio(0);
    d4 c00 = {0,0,0,0}, c01 = {0,0,0,0};
    d4 c10 = {0,0,0,0}, c11 = {0,0,0,0};
    FLOAD();
    for (int chp = 0; chp < 256; ++chp) {
        FSTAGE(As0, Bs0);
        __syncthreads();
        FLOAD();
        FMFMA(As0, Bs0);
        FSTAGE(As1, Bs1);
        __syncthreads();
        if (chp + 1 < 256) { FLOAD(); }
        FMFMA(As1, Bs1);
    }
#undef FLOAD
#undef FSTAGE
#undef FKSTEP
#undef FMFMA
    __syncthreads();
    double* Cred = (double*)smem;
#define CRED_OP(OP)                                                       \
    _Pragma("unroll")                                                     \
    for (int r = 0; r < 4; ++r) {                                         \
        const int ro = rowr[r], co = coff + colr[r];                      \
        Cred[(co     ) * 32 + ro     ] OP c00[r];                         \
        Cred[(co + 16) * 32 + ro     ] OP c01[r];                         \
        Cred[(co     ) * 32 + ro + 16] OP c10[r];                         \
        Cred[(co + 16) * 32 + ro + 16] OP c11[r];                         \
    }
    if (wid < 2)  { CRED_OP(=) }
    __syncthreads();
    if (wid >= 2) { CRED_OP(+=) }
    __syncthreads();
#undef CRED_OP
    const int scol = tid >> 2;
    const int srow = (tid & 3) * 8;
    const int tcol = tau0 + scol;
    if (tcol < T_STEPS) {
        const double* cp = &Cred[scol * 32 + srow];
        float4 o0, o1;
        o0.x = (float)cp[0]; o0.y = (float)cp[1]; o0.z = (float)cp[2]; o0.w = (float)cp[3];
        o1.x = (float)cp[4]; o1.y = (float)cp[5]; o1.z = (float)cp[6]; o1.w = (float)cp[7];
        float* op = &I0T[(size_t)tcol * N0 + n0 + srow];
        *reinterpret_cast<float4*>(op)     = o0;
        *reinterpret_cast<float4*>(op + 4) = o1;
    }
}

// ====== Kernel 2: layer-0 LIF scan -> bitpacked S0 + fp32 S0.T output (fused) ======
// One wave per block (64 threads), 64 blocks. Spike floats staged in a 64x65
// LDS tile per 64-t batch, then written COALESCED (lane = t within batch).
__global__ void lif0x(const float* __restrict__ I0T, uint32_t* __restrict__ S0P,
                      float* __restrict__ out) {
#pragma clang fp contract(off)
    __shared__ float tile[64][65];
    const int l  = threadIdx.x;          // lane = local neuron
    const int n0 = blockIdx.x * 64;
    const int n  = n0 + l;
    uint32_t* rowp = S0P + n * S0W;
    rowp[0] = 0u;
    rowp[20] = 0u; rowp[21] = 0u; rowp[22] = 0u; rowp[23] = 0u;
    float v = 0.0f;
    uint32_t word = 0;
    for (int b = 0; b < 10; ++b) {
        const int tbase = b * 64;
        const int tcnt  = (tbase + 64 <= T_STEPS) ? 64 : (T_STEPS - tbase);  // 64 or 23
        int u = 0;
        for (; u + 8 <= tcnt; u += 8) {
            float I[8];
#pragma unroll
            for (int k = 0; k < 8; ++k) I[k] = I0T[(size_t)(tbase + u + k) * N0 + n];
#pragma unroll
            for (int k = 0; k < 8; ++k) {
                const int tt = tbase + u + k;
                float a = v * 0.9f;            // separate rounding (match jnp)
                v = a + I[k];
                float s = 0.0f;
                if (v >= 1.0f) { word |= (1u << (tt & 31)); v = 0.0f; s = 1.0f; }
                tile[l][u + k] = s;
                if ((tt & 31) == 31) { rowp[1 + (tt >> 5)] = word; word = 0; }
            }
        }
        for (; u < tcnt; ++u) {
            const int tt = tbase + u;
            float I = I0T[(size_t)tt * N0 + n];
            float a = v * 0.9f;
            v = a + I;
            float s = 0.0f;
            if (v >= 1.0f) { word |= (1u << (tt & 31)); v = 0.0f; s = 1.0f; }
            tile[l][u] = s;
            if ((tt & 31) == 31) { rowp[1 + (tt >> 5)] = word; word = 0; }
        }
        __syncthreads();   // single wave: cheap; orders LDS writes vs reads
        if (l < tcnt) {
#pragma unroll 8
            for (int r = 0; r < 64; ++r)
                out[(size_t)(n0 + r) * T_STEPS + tbase + l] = tile[r][l];
        }
        __syncthreads();
    }
    rowp[1 + (T_STEPS >> 5)] = word;   // word 18 flush (bits 576..598)
}

// ====== Kernel 3: gather over an i-half -> fp64 partials ======
// Block bid = j*2 + half; sums i in [half*2048, half*2048+2048).
// 128 threads x 5 consecutive t (2-word window funnel, proven R12 body).
// Partials go to the dead I0T region: part[bid*599 + t] (exactly SZ_I0T).
__global__ __launch_bounds__(128) void gather_half(const float* __restrict__ W1,
                                                   const int* __restrict__ delays,
                                                   const uint32_t* __restrict__ S0P,
                                                   double* __restrict__ part) {
    __shared__ double  wl[2048];    // 16 KB
    __shared__ uint8_t dl[2048];    // 2 KB
    const int bid  = blockIdx.x;            // 0..2047
    const int j    = bid >> 1;
    const int ibase = (bid & 1) * 2048;
    const int tid  = threadIdx.x;
    for (int q = tid; q < 2048 / 4; q += 128) {
        const float4 w4 = *reinterpret_cast<const float4*>(&W1[(size_t)j * N0 + ibase + 4 * q]);
        wl[4 * q + 0] = (double)w4.x; wl[4 * q + 1] = (double)w4.y;
        wl[4 * q + 2] = (double)w4.z; wl[4 * q + 3] = (double)w4.w;
        const int4 dv = *reinterpret_cast<const int4*>(&delays[(size_t)j * N0 + ibase + 4 * q]);
        dl[4 * q + 0] = (uint8_t)dv.x; dl[4 * q + 1] = (uint8_t)dv.y;
        dl[4 * q + 2] = (uint8_t)dv.z; dl[4 * q + 3] = (uint8_t)dv.w;
    }
    __syncthreads();
    const int t5 = 5 * tid;                     // 0,5,...,595 (tid<120 active)
    double a0 = 0.0, a1 = 0.0, a2 = 0.0, a3 = 0.0, a4 = 0.0;
    const uint32_t* rp0 = S0P + (size_t)ibase * S0W + 1;   // +1 folds pad word
#pragma unroll 2
    for (int i = 0; i < 2048; ++i) {
        const int s0  = t5 - (int)dl[i];        // [-15, 595]
        const double w = wl[i];
        const int widx = (s0 >> 5);             // -1..18; bias makes it valid
        const int sh   = s0 & 31;
        const uint32_t lo = rp0[widx];
        const uint32_t hi = rp0[widx + 1];
        const uint32_t w5 = (uint32_t)(((((uint64_t)hi) << 32) | lo) >> sh);
        a0 = fma((double)( w5       & 1u), w, a0);
        a1 = fma((double)((w5 >> 1) & 1u), w, a1);
        a2 = fma((double)((w5 >> 2) & 1u), w, a2);
        a3 = fma((double)((w5 >> 3) & 1u), w, a3);
        a4 = fma((double)((w5 >> 4) & 1u), w, a4);
        rp0 += S0W;
    }
    if (tid < 120) {
        double* op = part + (size_t)bid * T_STEPS + t5;
        op[0] = a0; op[1] = a1; op[2] = a2; op[3] = a3;
        if (t5 + 4 < T_STEPS) op[4] = a4;       // tid==119: t=599 doesn't exist
    }
}

// ====== Kernel 4: combine halves + layer-1 LIF + S1 output ======
__global__ __launch_bounds__(64) void combine_lif1(const double* __restrict__ part,
                                                   float* __restrict__ out) {
#pragma clang fp contract(off)
    __shared__ float i1row[T_RAW];
    const int j = blockIdx.x;
    const int l = threadIdx.x;
    const double* p0 = part + (size_t)(2 * j)     * T_STEPS;
    const double* p1 = part + (size_t)(2 * j + 1) * T_STEPS;
    for (int t = l; t < T_STEPS; t += 64)
        i1row[t] = (float)(p0[t] + p1[t]);
    __syncthreads();
    if (l == 0) {
        float* o = out + (size_t)N0 * T_STEPS + (size_t)j * T_STEPS;
        float v = 0.0f;
        for (int t = 0; t < T_STEPS; ++t) {
            float a = v * 0.9f;                 // separate rounding (match jnp)
            v = a + i1row[t];
            float s = 0.0f;
            if (v >= 1.0f) { s = 1.0f; v = 0.0f; }
            o[t] = s;
        }
    }
}

extern "C" void kernel_launch(void* const* d_in, const int* in_sizes, int n_in,
                              void* d_out, int out_size, void* d_ws, size_t ws_size,
                              hipStream_t stream) {
    const float* stim   = (const float*)d_in[0];   // 128*128*600
    const float* W0     = (const float*)d_in[1];   // 4096*16384
    const float* W1     = (const float*)d_in[2];   // 1024*4096
    const int*   delays = (const int*)d_in[3];     // 1024*4096

    char* ws = (char*)d_ws;
    float*    I0T  = (float*)(ws + OFF_I0T);
    double*   part = (double*)(ws + OFF_I0T);      // reuses I0T after lif0x
    uint32_t* S0b  = (uint32_t*)(ws + OFF_S0B);
    float*    Xt   = (float*)(ws + OFF_XT);
    float*    out  = (float*)d_out;

    if (ws_size >= OFF_XT + SZ_XT) {
        hipLaunchKernelGGL(transpose_stim, dim3(10, 256), dim3(256), 0, stream, stim, Xt);
        hipLaunchKernelGGL(gemm_i0_xt,     dim3(1280),    dim3(256), 0, stream, W0, Xt, I0T);
    } else {
        hipLaunchKernelGGL(gemm_i0_fb,     dim3(1280),    dim3(256), 0, stream, W0, stim, I0T);
    }
    hipLaunchKernelGGL(lif0x,        dim3(64),   dim3(64),  0, stream, I0T, S0b, out);
    hipLaunchKernelGGL(gather_half,  dim3(2048), dim3(128), 0, stream, W1, delays, S0b, part);
    hipLaunchKernelGGL(combine_lif1, dim3(1024), dim3(64),  0, stream, part, out);
}

// Round 14
// 1799.966 us; speedup vs baseline: 1.3177x; 1.0337x over previous
//
#include <hip/hip_runtime.h>
#include <stdint.h>
#include <math.h>

#define T_STEPS 599   // T-1 scan steps (x[1:])
#define T_RAW   600
#define NIN     16384
#define N0      4096
#define N1      1024
#define S0W     24    // padded words per S0 row: [pad0][19 spike words][4 zero]
#define TAUP    640   // padded tau extent of Xt

typedef double d4 __attribute__((ext_vector_type(4)));

// ---- workspace layout (bytes) ----
static const size_t OFF_I0T = 0;
static const size_t SZ_I0T  = (size_t)T_STEPS * N0 * 4;      // 9,814,016
static const size_t OFF_S0B = OFF_I0T + SZ_I0T;
static const size_t SZ_S0B  = (size_t)N0 * S0W * 4;          // 393,216
static const size_t OFF_XT  = OFF_S0B + SZ_S0B;
static const size_t SZ_XT   = (size_t)TAUP * NIN * 4;        // 41,943,040 (~52.3 MB total)
// quarter-gather partials: 4096 x 599 fp64 = 19.6 MB, reuses the Xt region
// (dead after gemm_i0_xt completes; same-stream ordering guarantees safety)
static const size_t SZ_PARTQ = (size_t)4096 * T_STEPS * 8;

// ====== Kernel 0: transpose stim[k][tau] -> Xt[tau][k] (bakes +1 shift, zero pad) ======
__global__ __launch_bounds__(256) void transpose_stim(const float* __restrict__ stim,
                                                      float* __restrict__ Xt) {
    __shared__ float T[64][65];
    const int tau0 = blockIdx.x * 64;   // 0..576 (10 blocks)
    const int k0   = blockIdx.y * 64;   // 0..16320 (256 blocks)
    const int tid  = threadIdx.x;
    const int kk = tid >> 2;
    const int tb = tid & 3;
#pragma unroll
    for (int q = 0; q < 16; ++q) {
        const int tl = tb + 4 * q;
        const int tg = tau0 + tl;
        float v = 0.0f;
        if (tg <= T_STEPS - 1) v = stim[(size_t)(k0 + kk) * T_RAW + tg + 1];
        T[kk][tl] = v;
    }
    __syncthreads();
    const int tt = tid >> 2;
    const int kq = (tid & 3) * 16;
#pragma unroll
    for (int j = 0; j < 4; ++j) {
        const int kl = kq + 4 * j;
        float4 o;
        o.x = T[kl + 0][tt]; o.y = T[kl + 1][tt];
        o.z = T[kl + 2][tt]; o.w = T[kl + 3][tt];
        *reinterpret_cast<float4*>(&Xt[(size_t)(tau0 + tt) * NIN + k0 + kl]) = o;
    }
}

// ====== Kernel 1 (fast): I0 = W0 @ X, fp64 MFMA, all-b128 LDS reads (R12-exact) ======
__global__ __launch_bounds__(256, 5) void gemm_i0_xt(const float* __restrict__ W0,
                                                     const float* __restrict__ Xt,
                                                     float* __restrict__ I0T) {
    __shared__ __align__(16) char smem[31744];
    float* As0 = (float*)(smem);             // 32*36*4 = 4608
    float* As1 = (float*)(smem + 4608);
    float* Bt0 = (float*)(smem + 9216);      // 64*44*4 = 11264
    float* Bt1 = (float*)(smem + 20480);
    const int tid  = threadIdx.x;
    const int lane = tid & 63;
    const int wid  = tid >> 6;
    const int kbase = 16 * (wid >> 1);       // k half: 0 or 16
    const int coff  = 32 * (wid & 1);        // tau half: 0 or 32
    const int flat = blockIdx.x;
    const int idx  = (flat & 7) * 160 + (flat >> 3);   // XCD swizzle (1280%8==0)
    const int n0   = (idx / 10) * 32;
    const int tau0 = (idx % 10) * 64;
    const int r15  = lane & 15;
    const int c    = lane >> 4;              // MFMA slot 0..3

    // ---- probe the C/D layout of v_mfma_f64_16x16x4f64 (proven R3) ----
    d4 zero = {0.0, 0.0, 0.0, 0.0};
    const double ap1 = (c == 0) ? 1.0 : 0.0;
    const double bp1 = (c == 0) ? (double)r15 : 0.0;
    d4 pcol = __builtin_amdgcn_mfma_f64_16x16x4f64(ap1, bp1, zero, 0, 0, 0);
    const double ap2 = (c == 0) ? (double)r15 : 0.0;
    const double bp2 = (c == 0) ? 1.0 : 0.0;
    d4 prow = __builtin_amdgcn_mfma_f64_16x16x4f64(ap2, bp2, zero, 0, 0, 0);
    int rowr[4], colr[4];
#pragma unroll
    for (int r = 0; r < 4; ++r) {
        int cc = (int)pcol[r]; cc = cc < 0 ? 0 : (cc > 15 ? 15 : cc);
        int rw = (int)prow[r]; rw = rw < 0 ? 0 : (rw > 15 ? 15 : rw);
        colr[r] = cc; rowr[r] = rw;
    }

    const int ar   = tid >> 3;           // A row 0..31
    const int ac4  = (tid & 7) * 4;      // A k-col (float4)
    const int btau = tid >> 2;           // B tau row 0..63
    const int bk8  = (tid & 3) * 8;      // B k-col base (2 float4)

    const float* aP  = W0 + (size_t)(n0 + ar) * NIN + ac4;
    const float* xP  = Xt + (size_t)(tau0 + btau) * NIN + bk8;

    float4 aR, bR0, bR1;                 // named staging regs (NO arrays)

#define XLOAD()                                                           \
    aR  = *reinterpret_cast<const float4*>(aP);                           \
    bR0 = *reinterpret_cast<const float4*>(xP);                           \
    bR1 = *reinterpret_cast<const float4*>(xP + 4);                       \
    aP += 32; xP += 32;

#define XSTAGE(AS, BS)                                                    \
    *reinterpret_cast<float4*>(&AS[ar * 36 + ac4]) = aR;                  \
    *reinterpret_cast<float4*>(&BS[btau * 44 + bk8]) = bR0;               \
    *reinterpret_cast<float4*>(&BS[btau * 44 + bk8 + 4]) = bR1;

    d4 c00 = {0,0,0,0}, c01 = {0,0,0,0};
    d4 c10 = {0,0,0,0}, c11 = {0,0,0,0};

#define XMFMA(AS, BS)                                                     \
    {                                                                     \
        __builtin_amdgcn_s_setprio(1);                                    \
        const float4 a0f = *reinterpret_cast<const float4*>(&AS[r15 * 36 + kbase + 4 * c]);        \
        const float4 a1f = *reinterpret_cast<const float4*>(&AS[(16 + r15) * 36 + kbase + 4 * c]); \
        const float4 b0f = *reinterpret_cast<const float4*>(&BS[(coff + r15) * 44 + kbase + 4 * c]);      \
        const float4 b1f = *reinterpret_cast<const float4*>(&BS[(coff + 16 + r15) * 44 + kbase + 4 * c]); \
        c00 = __builtin_amdgcn_mfma_f64_16x16x4f64((double)a0f.x, (double)b0f.x, c00, 0, 0, 0);    \
        c01 = __builtin_amdgcn_mfma_f64_16x16x4f64((double)a0f.x, (double)b1f.x, c01, 0, 0, 0);    \
        c10 = __builtin_amdgcn_mfma_f64_16x16x4f64((double)a1f.x, (double)b0f.x, c10, 0, 0, 0);    \
        c11 = __builtin_amdgcn_mfma_f64_16x16x4f64((double)a1f.x, (double)b1f.x, c11, 0, 0, 0);    \
        c00 = __builtin_amdgcn_mfma_f64_16x16x4f64((double)a0f.y, (double)b0f.y, c00, 0, 0, 0);    \
        c01 = __builtin_amdgcn_mfma_f64_16x16x4f64((double)a0f.y, (double)b1f.y, c01, 0, 0, 0);    \
        c10 = __builtin_amdgcn_mfma_f64_16x16x4f64((double)a1f.y, (double)b0f.y, c10, 0, 0, 0);    \
        c11 = __builtin_amdgcn_mfma_f64_16x16x4f64((double)a1f.y, (double)b1f.y, c11, 0, 0, 0);    \
        c00 = __builtin_amdgcn_mfma_f64_16x16x4f64((double)a0f.z, (double)b0f.z, c00, 0, 0, 0);    \
        c01 = __builtin_amdgcn_mfma_f64_16x16x4f64((double)a0f.z, (double)b1f.z, c01, 0, 0, 0);    \
        c10 = __builtin_amdgcn_mfma_f64_16x16x4f64((double)a1f.z, (double)b0f.z, c10, 0, 0, 0);    \
        c11 = __builtin_amdgcn_mfma_f64_16x16x4f64((double)a1f.z, (double)b1f.z, c11, 0, 0, 0);    \
        c00 = __builtin_amdgcn_mfma_f64_16x16x4f64((double)a0f.w, (double)b0f.w, c00, 0, 0, 0);    \
        c01 = __builtin_amdgcn_mfma_f64_16x16x4f64((double)a0f.w, (double)b1f.w, c01, 0, 0, 0);    \
        c10 = __builtin_amdgcn_mfma_f64_16x16x4f64((double)a1f.w, (double)b0f.w, c10, 0, 0, 0);    \
        c11 = __builtin_amdgcn_mfma_f64_16x16x4f64((double)a1f.w, (double)b1f.w, c11, 0, 0, 0);    \
        __builtin_amdgcn_s_setprio(0);                                    \
    }

    XLOAD();                             // prologue: chunk 0
    for (int chp = 0; chp < 256; ++chp) {
        XSTAGE(As0, Bt0);
        __syncthreads();
        XLOAD();
        XMFMA(As0, Bt0);
        XSTAGE(As1, Bt1);
        __syncthreads();
        if (chp + 1 < 256) { XLOAD(); }
        XMFMA(As1, Bt1);
    }
#undef XLOAD
#undef XSTAGE
#undef XMFMA

    __syncthreads();
    double* Cred = (double*)smem;        // 64*32*8 = 16384 <= 31744

#define CRED_OP(OP)                                                       \
    _Pragma("unroll")                                                     \
    for (int r = 0; r < 4; ++r) {                                         \
        const int ro = rowr[r], co = coff + colr[r];                      \
        Cred[(co     ) * 32 + ro     ] OP c00[r];                         \
        Cred[(co + 16) * 32 + ro     ] OP c01[r];                         \
        Cred[(co     ) * 32 + ro + 16] OP c10[r];                         \
        Cred[(co + 16) * 32 + ro + 16] OP c11[r];                         \
    }
    if (wid < 2)  { CRED_OP(=) }
    __syncthreads();
    if (wid >= 2) { CRED_OP(+=) }
    __syncthreads();
#undef CRED_OP

    const int scol = tid >> 2;
    const int srow = (tid & 3) * 8;
    const int tcol = tau0 + scol;
    if (tcol < T_STEPS) {
        const double* cp = &Cred[scol * 32 + srow];
        float4 o0, o1;
        o0.x = (float)cp[0]; o0.y = (float)cp[1]; o0.z = (float)cp[2]; o0.w = (float)cp[3];
        o1.x = (float)cp[4]; o1.y = (float)cp[5]; o1.z = (float)cp[6]; o1.w = (float)cp[7];
        float* op = &I0T[(size_t)tcol * N0 + n0 + srow];
        *reinterpret_cast<float4*>(op)     = o0;
        *reinterpret_cast<float4*>(op + 4) = o1;
    }
}

// ====== Kernel 1 (fallback, R9-exact): used only if ws too small for Xt ======
__global__ __launch_bounds__(256, 5) void gemm_i0_fb(const float* __restrict__ W0,
                                                     const float* __restrict__ stim,
                                                     float* __restrict__ I0T) {
    __shared__ __align__(16) char smem[27904];
    float* As0 = (float*)(smem);
    float* As1 = (float*)(smem + 4736);
    float* Bs0 = (float*)(smem + 9472);
    float* Bs1 = (float*)(smem + 18688);
    const int tid  = threadIdx.x;
    const int lane = tid & 63;
    const int wid  = tid >> 6;
    const int kbase = 16 * (wid >> 1);
    const int coff  = 32 * (wid & 1);
    const int flat = blockIdx.x;
    const int idx  = (flat & 7) * 160 + (flat >> 3);
    const int n0   = (idx / 10) * 32;
    const int tau0 = (idx % 10) * 64;
    const int r15  = lane & 15;
    const int c    = lane >> 4;
    d4 zero = {0.0, 0.0, 0.0, 0.0};
    const double ap1 = (c == 0) ? 1.0 : 0.0;
    const double bp1 = (c == 0) ? (double)r15 : 0.0;
    d4 pcol = __builtin_amdgcn_mfma_f64_16x16x4f64(ap1, bp1, zero, 0, 0, 0);
    const double ap2 = (c == 0) ? (double)r15 : 0.0;
    const double bp2 = (c == 0) ? 1.0 : 0.0;
    d4 prow = __builtin_amdgcn_mfma_f64_16x16x4f64(ap2, bp2, zero, 0, 0, 0);
    int rowr[4], colr[4];
#pragma unroll
    for (int r = 0; r < 4; ++r) {
        int cc = (int)pcol[r]; cc = cc < 0 ? 0 : (cc > 15 ? 15 : cc);
        int rw = (int)prow[r]; rw = rw < 0 ? 0 : (rw > 15 ? 15 : rw);
        colr[r] = cc; rowr[r] = rw;
    }
    const int ar  = tid >> 3;
    const int ac4 = (tid & 7) * 4;
    const int br  = tid >> 4;
    const int bc4 = (tid & 15) * 4;
    const int t0g = tau0 + bc4;
    const bool fastB = (tau0 + 68) <= T_RAW;
    const float* aP  = W0 + (size_t)(n0 + ar) * NIN + ac4;
    const float* bP0 = stim + (size_t)br * T_RAW + t0g;
    const float* bP1 = stim + (size_t)(br + 16) * T_RAW + t0g;
    float4 aR, bRa, bRb;
#define FLOAD()                                                           \
    aR = *reinterpret_cast<const float4*>(aP);                            \
    if (fastB) {                                                          \
        float4 f0 = *reinterpret_cast<const float4*>(bP0);                \
        float  e0 = bP0[4];                                               \
        bRa.x = f0.y; bRa.y = f0.z; bRa.z = f0.w; bRa.w = e0;             \
        float4 f1 = *reinterpret_cast<const float4*>(bP1);                \
        float  e1 = bP1[4];                                               \
        bRb.x = f1.y; bRb.y = f1.z; bRb.z = f1.w; bRb.w = e1;             \
    } else {                                                              \
        bRa.x = (t0g + 0 < T_STEPS) ? bP0[1] : 0.0f;                      \
        bRa.y = (t0g + 1 < T_STEPS) ? bP0[2] : 0.0f;                      \
        bRa.z = (t0g + 2 < T_STEPS) ? bP0[3] : 0.0f;                      \
        bRa.w = (t0g + 3 < T_STEPS) ? bP0[4] : 0.0f;                      \
        bRb.x = (t0g + 0 < T_STEPS) ? bP1[1] : 0.0f;                      \
        bRb.y = (t0g + 1 < T_STEPS) ? bP1[2] : 0.0f;                      \
        bRb.z = (t0g + 2 < T_STEPS) ? bP1[3] : 0.0f;                      \
        bRb.w = (t0g + 3 < T_STEPS) ? bP1[4] : 0.0f;                      \
    }                                                                     \
    aP += 32; bP0 += 32 * T_RAW; bP1 += 32 * T_RAW;
#define FSTAGE(AS, BS)                                                    \
    *reinterpret_cast<float4*>(&AS[ar * 37 + ac4]) = aR;                  \
    *reinterpret_cast<float4*>(&BS[br * 72 + bc4]) = bRa;                 \
    *reinterpret_cast<float4*>(&BS[(br + 16) * 72 + bc4]) = bRb;
#define FKSTEP(AS, BS, KK)                                                \
    {                                                                     \
        const double a0 = (double)AS[r15 * 37 + (KK)];                    \
        const double a1 = (double)AS[(16 + r15) * 37 + (KK)];             \
        const double b0 = (double)BS[(KK) * 72 + coff + r15];             \
        const double b1 = (double)BS[(KK) * 72 + coff + 16 + r15];        \
        c00 = __builtin_amdgcn_mfma_f64_16x16x4f64(a0, b0, c00, 0, 0, 0); \
        c01 = __builtin_amdgcn_mfma_f64_16x16x4f64(a0, b1, c01, 0, 0, 0); \
        c10 = __builtin_amdgcn_mfma_f64_16x16x4f64(a1, b0, c10, 0, 0, 0); \
        c11 = __builtin_amdgcn_mfma_f64_16x16x4f64(a1, b1, c11, 0, 0, 0); \
    }
#define FMFMA(AS, BS)                                                     \
    __builtin_amdgcn_s_setprio(1);                                        \
    FKSTEP(AS, BS, kbase + c);                                            \
    FKSTEP(AS, BS, kbase + 4 + c);                                        \
    FKSTEP(AS, BS, kbase + 8 + c);                                        \
    FKSTEP(AS, BS, kbase + 12 + c);                                       \
    __builtin_amdgcn_s_setprio(0);
    d4 c00 = {0,0,0,0}, c01 = {0,0,0,0};
    d4 c10 = {0,0,0,0}, c11 = {0,0,0,0};
    FLOAD();
    for (int chp = 0; chp < 256; ++chp) {
        FSTAGE(As0, Bs0);
        __syncthreads();
        FLOAD();
        FMFMA(As0, Bs0);
        FSTAGE(As1, Bs1);
        __syncthreads();
        if (chp + 1 < 256) { FLOAD(); }
        FMFMA(As1, Bs1);
    }
#undef FLOAD
#undef FSTAGE
#undef FKSTEP
#undef FMFMA
    __syncthreads();
    double* Cred = (double*)smem;
#define CRED_OP(OP)                                                       \
    _Pragma("unroll")                                                     \
    for (int r = 0; r < 4; ++r) {                                         \
        const int ro = rowr[r], co = coff + colr[r];                      \
        Cred[(co     ) * 32 + ro     ] OP c00[r];                         \
        Cred[(co + 16) * 32 + ro     ] OP c01[r];                         \
        Cred[(co     ) * 32 + ro + 16] OP c10[r];                         \
        Cred[(co + 16) * 32 + ro + 16] OP c11[r];                         \
    }
    if (wid < 2)  { CRED_OP(=) }
    __syncthreads();
    if (wid >= 2) { CRED_OP(+=) }
    __syncthreads();
#undef CRED_OP
    const int scol = tid >> 2;
    const int srow = (tid & 3) * 8;
    const int tcol = tau0 + scol;
    if (tcol < T_STEPS) {
        const double* cp = &Cred[scol * 32 + srow];
        float4 o0, o1;
        o0.x = (float)cp[0]; o0.y = (float)cp[1]; o0.z = (float)cp[2]; o0.w = (float)cp[3];
        o1.x = (float)cp[4]; o1.y = (float)cp[5]; o1.z = (float)cp[6]; o1.w = (float)cp[7];
        float* op = &I0T[(size_t)tcol * N0 + n0 + srow];
        *reinterpret_cast<float4*>(op)     = o0;
        *reinterpret_cast<float4*>(op + 4) = o1;
    }
}

// ====== Kernel 2: layer-0 LIF scan -> bitpacked S0 + fp32 S0.T output (R13-exact) ======
__global__ void lif0x(const float* __restrict__ I0T, uint32_t* __restrict__ S0P,
                      float* __restrict__ out) {
#pragma clang fp contract(off)
    __shared__ float tile[64][65];
    const int l  = threadIdx.x;          // lane = local neuron
    const int n0 = blockIdx.x * 64;
    const int n  = n0 + l;
    uint32_t* rowp = S0P + n * S0W;
    rowp[0] = 0u;
    rowp[20] = 0u; rowp[21] = 0u; rowp[22] = 0u; rowp[23] = 0u;
    float v = 0.0f;
    uint32_t word = 0;
    for (int b = 0; b < 10; ++b) {
        const int tbase = b * 64;
        const int tcnt  = (tbase + 64 <= T_STEPS) ? 64 : (T_STEPS - tbase);  // 64 or 23
        int u = 0;
        for (; u + 8 <= tcnt; u += 8) {
            float I[8];
#pragma unroll
            for (int k = 0; k < 8; ++k) I[k] = I0T[(size_t)(tbase + u + k) * N0 + n];
#pragma unroll
            for (int k = 0; k < 8; ++k) {
                const int tt = tbase + u + k;
                float a = v * 0.9f;            // separate rounding (match jnp)
                v = a + I[k];
                float s = 0.0f;
                if (v >= 1.0f) { word |= (1u << (tt & 31)); v = 0.0f; s = 1.0f; }
                tile[l][u + k] = s;
                if ((tt & 31) == 31) { rowp[1 + (tt >> 5)] = word; word = 0; }
            }
        }
        for (; u < tcnt; ++u) {
            const int tt = tbase + u;
            float I = I0T[(size_t)tt * N0 + n];
            float a = v * 0.9f;
            v = a + I;
            float s = 0.0f;
            if (v >= 1.0f) { word |= (1u << (tt & 31)); v = 0.0f; s = 1.0f; }
            tile[l][u] = s;
            if ((tt & 31) == 31) { rowp[1 + (tt >> 5)] = word; word = 0; }
        }
        __syncthreads();
        if (l < tcnt) {
#pragma unroll 8
            for (int r = 0; r < 64; ++r)
                out[(size_t)(n0 + r) * T_STEPS + tbase + l] = tile[r][l];
        }
        __syncthreads();
    }
    rowp[1 + (T_STEPS >> 5)] = word;   // word 18 flush (bits 576..598)
}

// ====== Kernel 3a (fast): gather over an i-QUARTER -> fp64 partials ======
// Block bid = j*4 + q; sums i in [q*1024, q*1024+1024). 4096 blocks x 2 waves
// = 32 waves/CU (HW max) -> halves per-wave serial work vs halves.
// Partials -> Xt region (dead after gemm). LDS 9.25 KB.
__global__ __launch_bounds__(128) void gather_q(const float* __restrict__ W1,
                                                const int* __restrict__ delays,
                                                const uint32_t* __restrict__ S0P,
                                                double* __restrict__ part) {
    __shared__ double  wl[1024];    // 8 KB
    __shared__ uint8_t dl[1024];    // 1 KB
    const int bid   = blockIdx.x;           // 0..4095
    const int j     = bid >> 2;
    const int ibase = (bid & 3) * 1024;
    const int tid   = threadIdx.x;
    for (int q = tid; q < 1024 / 4; q += 128) {
        const float4 w4 = *reinterpret_cast<const float4*>(&W1[(size_t)j * N0 + ibase + 4 * q]);
        wl[4 * q + 0] = (double)w4.x; wl[4 * q + 1] = (double)w4.y;
        wl[4 * q + 2] = (double)w4.z; wl[4 * q + 3] = (double)w4.w;
        const int4 dv = *reinterpret_cast<const int4*>(&delays[(size_t)j * N0 + ibase + 4 * q]);
        dl[4 * q + 0] = (uint8_t)dv.x; dl[4 * q + 1] = (uint8_t)dv.y;
        dl[4 * q + 2] = (uint8_t)dv.z; dl[4 * q + 3] = (uint8_t)dv.w;
    }
    __syncthreads();
    const int t5 = 5 * tid;                     // 0,5,...,595 (tid<120 active)
    double a0 = 0.0, a1 = 0.0, a2 = 0.0, a3 = 0.0, a4 = 0.0;
    const uint32_t* rp0 = S0P + (size_t)ibase * S0W + 1;   // +1 folds pad word
#pragma unroll 4
    for (int i = 0; i < 1024; ++i) {
        const int s0  = t5 - (int)dl[i];        // [-15, 595]
        const double w = wl[i];
        const int widx = (s0 >> 5);             // -1..18; bias makes it valid
        const int sh   = s0 & 31;
        const uint32_t lo = rp0[widx];
        const uint32_t hi = rp0[widx + 1];
        const uint32_t w5 = (uint32_t)(((((uint64_t)hi) << 32) | lo) >> sh);
        a0 = fma((double)( w5       & 1u), w, a0);
        a1 = fma((double)((w5 >> 1) & 1u), w, a1);
        a2 = fma((double)((w5 >> 2) & 1u), w, a2);
        a3 = fma((double)((w5 >> 3) & 1u), w, a3);
        a4 = fma((double)((w5 >> 4) & 1u), w, a4);
        rp0 += S0W;
    }
    if (tid < 120) {
        double* op = part + (size_t)bid * T_STEPS + t5;
        op[0] = a0; op[1] = a1; op[2] = a2; op[3] = a3;
        if (t5 + 4 < T_STEPS) op[4] = a4;
    }
}

// ====== Kernel 4a (fast): combine 4 quarters + layer-1 LIF + S1 output ======
__global__ __launch_bounds__(64) void combine_lif1_q(const double* __restrict__ part,
                                                     float* __restrict__ out) {
#pragma clang fp contract(off)
    __shared__ float i1row[T_RAW];
    const int j = blockIdx.x;
    const int l = threadIdx.x;
    const double* p0 = part + (size_t)(4 * j)     * T_STEPS;
    const double* p1 = part + (size_t)(4 * j + 1) * T_STEPS;
    const double* p2 = part + (size_t)(4 * j + 2) * T_STEPS;
    const double* p3 = part + (size_t)(4 * j + 3) * T_STEPS;
    for (int t = l; t < T_STEPS; t += 64)
        i1row[t] = (float)(p0[t] + p1[t] + p2[t] + p3[t]);
    __syncthreads();
    if (l == 0) {
        float* o = out + (size_t)N0 * T_STEPS + (size_t)j * T_STEPS;
        float v = 0.0f;
        for (int t = 0; t < T_STEPS; ++t) {
            float a = v * 0.9f;                 // separate rounding (match jnp)
            v = a + i1row[t];
            float s = 0.0f;
            if (v >= 1.0f) { s = 1.0f; v = 0.0f; }
            o[t] = s;
        }
    }
}

// ====== Kernel 3b/4b (fallback): half-split gather into I0T region (R13-exact) ======
__global__ __launch_bounds__(128) void gather_half(const float* __restrict__ W1,
                                                   const int* __restrict__ delays,
                                                   const uint32_t* __restrict__ S0P,
                                                   double* __restrict__ part) {
    __shared__ double  wl[2048];
    __shared__ uint8_t dl[2048];
    const int bid  = blockIdx.x;
    const int j    = bid >> 1;
    const int ibase = (bid & 1) * 2048;
    const int tid  = threadIdx.x;
    for (int q = tid; q < 2048 / 4; q += 128) {
        const float4 w4 = *reinterpret_cast<const float4*>(&W1[(size_t)j * N0 + ibase + 4 * q]);
        wl[4 * q + 0] = (double)w4.x; wl[4 * q + 1] = (double)w4.y;
        wl[4 * q + 2] = (double)w4.z; wl[4 * q + 3] = (double)w4.w;
        const int4 dv = *reinterpret_cast<const int4*>(&delays[(size_t)j * N0 + ibase + 4 * q]);
        dl[4 * q + 0] = (uint8_t)dv.x; dl[4 * q + 1] = (uint8_t)dv.y;
        dl[4 * q + 2] = (uint8_t)dv.z; dl[4 * q + 3] = (uint8_t)dv.w;
    }
    __syncthreads();
    const int t5 = 5 * tid;
    double a0 = 0.0, a1 = 0.0, a2 = 0.0, a3 = 0.0, a4 = 0.0;
    const uint32_t* rp0 = S0P + (size_t)ibase * S0W + 1;
#pragma unroll 2
    for (int i = 0; i < 2048; ++i) {
        const int s0  = t5 - (int)dl[i];
        const double w = wl[i];
        const int widx = (s0 >> 5);
        const int sh   = s0 & 31;
        const uint32_t lo = rp0[widx];
        const uint32_t hi = rp0[widx + 1];
        const uint32_t w5 = (uint32_t)(((((uint64_t)hi) << 32) | lo) >> sh);
        a0 = fma((double)( w5       & 1u), w, a0);
        a1 = fma((double)((w5 >> 1) & 1u), w, a1);
        a2 = fma((double)((w5 >> 2) & 1u), w, a2);
        a3 = fma((double)((w5 >> 3) & 1u), w, a3);
        a4 = fma((double)((w5 >> 4) & 1u), w, a4);
        rp0 += S0W;
    }
    if (tid < 120) {
        double* op = part + (size_t)bid * T_STEPS + t5;
        op[0] = a0; op[1] = a1; op[2] = a2; op[3] = a3;
        if (t5 + 4 < T_STEPS) op[4] = a4;
    }
}

__global__ __launch_bounds__(64) void combine_lif1_h(const double* __restrict__ part,
                                                     float* __restrict__ out) {
#pragma clang fp contract(off)
    __shared__ float i1row[T_RAW];
    const int j = blockIdx.x;
    const int l = threadIdx.x;
    const double* p0 = part + (size_t)(2 * j)     * T_STEPS;
    const double* p1 = part + (size_t)(2 * j + 1) * T_STEPS;
    for (int t = l; t < T_STEPS; t += 64)
        i1row[t] = (float)(p0[t] + p1[t]);
    __syncthreads();
    if (l == 0) {
        float* o = out + (size_t)N0 * T_STEPS + (size_t)j * T_STEPS;
        float v = 0.0f;
        for (int t = 0; t < T_STEPS; ++t) {
            float a = v * 0.9f;
            v = a + i1row[t];
            float s = 0.0f;
            if (v >= 1.0f) { s = 1.0f; v = 0.0f; }
            o[t] = s;
        }
    }
}

extern "C" void kernel_launch(void* const* d_in, const int* in_sizes, int n_in,
                              void* d_out, int out_size, void* d_ws, size_t ws_size,
                              hipStream_t stream) {
    const float* stim   = (const float*)d_in[0];   // 128*128*600
    const float* W0     = (const float*)d_in[1];   // 4096*16384
    const float* W1     = (const float*)d_in[2];   // 1024*4096
    const int*   delays = (const int*)d_in[3];     // 1024*4096

    char* ws = (char*)d_ws;
    float*    I0T   = (float*)(ws + OFF_I0T);
    uint32_t* S0b   = (uint32_t*)(ws + OFF_S0B);
    float*    Xt    = (float*)(ws + OFF_XT);
    double*   partQ = (double*)(ws + OFF_XT);      // reuses Xt region after gemm
    double*   partH = (double*)(ws + OFF_I0T);     // reuses I0T region (fallback)
    float*    out   = (float*)d_out;

    if (ws_size >= OFF_XT + SZ_XT) {
        hipLaunchKernelGGL(transpose_stim, dim3(10, 256), dim3(256), 0, stream, stim, Xt);
        hipLaunchKernelGGL(gemm_i0_xt,     dim3(1280),    dim3(256), 0, stream, W0, Xt, I0T);
        hipLaunchKernelGGL(lif0x,          dim3(64),      dim3(64),  0, stream, I0T, S0b, out);
        hipLaunchKernelGGL(gather_q,       dim3(4096),    dim3(128), 0, stream, W1, delays, S0b, partQ);
        hipLaunchKernelGGL(combine_lif1_q, dim3(1024),    dim3(64),  0, stream, partQ, out);
    } else {
        hipLaunchKernelGGL(gemm_i0_fb,     dim3(1280),    dim3(256), 0, stream, W0, stim, I0T);
        hipLaunchKernelGGL(lif0x,          dim3(64),      dim3(64),  0, stream, I0T, S0b, out);
        hipLaunchKernelGGL(gather_half,    dim3(2048),    dim3(128), 0, stream, W1, delays, S0b, partH);
        hipLaunchKernelGGL(combine_lif1_h, dim3(1024),    dim3(64),  0, stream, partH, out);
    }
}

// Round 15
// 1769.271 us; speedup vs baseline: 1.3406x; 1.0173x over previous
//
#include <hip/hip_runtime.h>
#include <stdint.h>
#include <math.h>

#define T_STEPS 599   // T-1 scan steps (x[1:])
#define T_RAW   600
#define NIN     16384
#define N0      4096
#define N1      1024
#define S0W     24    // padded words per S0 row: [pad0][19 spike words][4 zero]
#define TAUP    640   // padded tau extent of Xt

typedef double d4 __attribute__((ext_vector_type(4)));

// ---- workspace layout (bytes) ----
static const size_t OFF_I0T = 0;
static const size_t SZ_I0T  = (size_t)T_STEPS * N0 * 4;      // 9,814,016
static const size_t OFF_S0B = OFF_I0T + SZ_I0T;
static const size_t SZ_S0B  = (size_t)N0 * S0W * 4;          // 393,216
static const size_t OFF_XT  = OFF_S0B + SZ_S0B;
static const size_t SZ_XT   = (size_t)TAUP * NIN * 4;        // 41,943,040 (~52.3 MB total)

// ====== Kernel 0: transpose stim[k][tau] -> Xt[tau][k], COALESCED loads ======
// Lane = tau: each load instruction reads 64 consecutive floats of one k-row.
__global__ __launch_bounds__(256) void transpose_stim(const float* __restrict__ stim,
                                                      float* __restrict__ Xt) {
    __shared__ float T[64][65];
    const int tau0 = blockIdx.x * 64;   // 0..576 (10 blocks)
    const int k0   = blockIdx.y * 64;   // 0..16320 (256 blocks)
    const int tid  = threadIdx.x;
    const int tl = tid & 63;            // tau lane
    const int kq = tid >> 6;            // wave id 0..3
    const int tg = tau0 + tl;
    const bool valid = (tg < T_STEPS);
#pragma unroll
    for (int i = 0; i < 16; ++i) {
        const int kk = kq + 4 * i;      // rows kq, kq+4, ...
        float v = valid ? stim[(size_t)(k0 + kk) * T_RAW + tg + 1] : 0.0f;
        T[kk][tl] = v;                  // row-write, conflict-free
    }
    __syncthreads();
    const int tt = tid >> 2;
    const int kcol = (tid & 3) * 16;
#pragma unroll
    for (int j = 0; j < 4; ++j) {
        const int kl = kcol + 4 * j;
        float4 o;
        o.x = T[kl + 0][tt]; o.y = T[kl + 1][tt];
        o.z = T[kl + 2][tt]; o.w = T[kl + 3][tt];
        *reinterpret_cast<float4*>(&Xt[(size_t)(tau0 + tt) * NIN + k0 + kl]) = o;
    }
}

// ====== Kernel 1 (fast): I0 = W0 @ X, fp64 MFMA, all-b128 LDS reads (R12-exact) ======
__global__ __launch_bounds__(256, 5) void gemm_i0_xt(const float* __restrict__ W0,
                                                     const float* __restrict__ Xt,
                                                     float* __restrict__ I0T) {
    __shared__ __align__(16) char smem[31744];
    float* As0 = (float*)(smem);             // 32*36*4 = 4608
    float* As1 = (float*)(smem + 4608);
    float* Bt0 = (float*)(smem + 9216);      // 64*44*4 = 11264
    float* Bt1 = (float*)(smem + 20480);
    const int tid  = threadIdx.x;
    const int lane = tid & 63;
    const int wid  = tid >> 6;
    const int kbase = 16 * (wid >> 1);       // k half: 0 or 16
    const int coff  = 32 * (wid & 1);        // tau half: 0 or 32
    const int flat = blockIdx.x;
    const int idx  = (flat & 7) * 160 + (flat >> 3);   // XCD swizzle (1280%8==0)
    const int n0   = (idx / 10) * 32;
    const int tau0 = (idx % 10) * 64;
    const int r15  = lane & 15;
    const int c    = lane >> 4;              // MFMA slot 0..3

    // ---- probe the C/D layout of v_mfma_f64_16x16x4f64 (proven R3) ----
    d4 zero = {0.0, 0.0, 0.0, 0.0};
    const double ap1 = (c == 0) ? 1.0 : 0.0;
    const double bp1 = (c == 0) ? (double)r15 : 0.0;
    d4 pcol = __builtin_amdgcn_mfma_f64_16x16x4f64(ap1, bp1, zero, 0, 0, 0);
    const double ap2 = (c == 0) ? (double)r15 : 0.0;
    const double bp2 = (c == 0) ? 1.0 : 0.0;
    d4 prow = __builtin_amdgcn_mfma_f64_16x16x4f64(ap2, bp2, zero, 0, 0, 0);
    int rowr[4], colr[4];
#pragma unroll
    for (int r = 0; r < 4; ++r) {
        int cc = (int)pcol[r]; cc = cc < 0 ? 0 : (cc > 15 ? 15 : cc);
        int rw = (int)prow[r]; rw = rw < 0 ? 0 : (rw > 15 ? 15 : rw);
        colr[r] = cc; rowr[r] = rw;
    }

    const int ar   = tid >> 3;           // A row 0..31
    const int ac4  = (tid & 7) * 4;      // A k-col (float4)
    const int btau = tid >> 2;           // B tau row 0..63
    const int bk8  = (tid & 3) * 8;      // B k-col base (2 float4)

    const float* aP  = W0 + (size_t)(n0 + ar) * NIN + ac4;
    const float* xP  = Xt + (size_t)(tau0 + btau) * NIN + bk8;

    float4 aR, bR0, bR1;                 // named staging regs (NO arrays)

#define XLOAD()                                                           \
    aR  = *reinterpret_cast<const float4*>(aP);                           \
    bR0 = *reinterpret_cast<const float4*>(xP);                           \
    bR1 = *reinterpret_cast<const float4*>(xP + 4);                       \
    aP += 32; xP += 32;

#define XSTAGE(AS, BS)                                                    \
    *reinterpret_cast<float4*>(&AS[ar * 36 + ac4]) = aR;                  \
    *reinterpret_cast<float4*>(&BS[btau * 44 + bk8]) = bR0;               \
    *reinterpret_cast<float4*>(&BS[btau * 44 + bk8 + 4]) = bR1;

    d4 c00 = {0,0,0,0}, c01 = {0,0,0,0};
    d4 c10 = {0,0,0,0}, c11 = {0,0,0,0};

#define XMFMA(AS, BS)                                                     \
    {                                                                     \
        __builtin_amdgcn_s_setprio(1);                                    \
        const float4 a0f = *reinterpret_cast<const float4*>(&AS[r15 * 36 + kbase + 4 * c]);        \
        const float4 a1f = *reinterpret_cast<const float4*>(&AS[(16 + r15) * 36 + kbase + 4 * c]); \
        const float4 b0f = *reinterpret_cast<const float4*>(&BS[(coff + r15) * 44 + kbase + 4 * c]);      \
        const float4 b1f = *reinterpret_cast<const float4*>(&BS[(coff + 16 + r15) * 44 + kbase + 4 * c]); \
        c00 = __builtin_amdgcn_mfma_f64_16x16x4f64((double)a0f.x, (double)b0f.x, c00, 0, 0, 0);    \
        c01 = __builtin_amdgcn_mfma_f64_16x16x4f64((double)a0f.x, (double)b1f.x, c01, 0, 0, 0);    \
        c10 = __builtin_amdgcn_mfma_f64_16x16x4f64((double)a1f.x, (double)b0f.x, c10, 0, 0, 0);    \
        c11 = __builtin_amdgcn_mfma_f64_16x16x4f64((double)a1f.x, (double)b1f.x, c11, 0, 0, 0);    \
        c00 = __builtin_amdgcn_mfma_f64_16x16x4f64((double)a0f.y, (double)b0f.y, c00, 0, 0, 0);    \
        c01 = __builtin_amdgcn_mfma_f64_16x16x4f64((double)a0f.y, (double)b1f.y, c01, 0, 0, 0);    \
        c10 = __builtin_amdgcn_mfma_f64_16x16x4f64((double)a1f.y, (double)b0f.y, c10, 0, 0, 0);    \
        c11 = __builtin_amdgcn_mfma_f64_16x16x4f64((double)a1f.y, (double)b1f.y, c11, 0, 0, 0);    \
        c00 = __builtin_amdgcn_mfma_f64_16x16x4f64((double)a0f.z, (double)b0f.z, c00, 0, 0, 0);    \
        c01 = __builtin_amdgcn_mfma_f64_16x16x4f64((double)a0f.z, (double)b1f.z, c01, 0, 0, 0);    \
        c10 = __builtin_amdgcn_mfma_f64_16x16x4f64((double)a1f.z, (double)b0f.z, c10, 0, 0, 0);    \
        c11 = __builtin_amdgcn_mfma_f64_16x16x4f64((double)a1f.z, (double)b1f.z, c11, 0, 0, 0);    \
        c00 = __builtin_amdgcn_mfma_f64_16x16x4f64((double)a0f.w, (double)b0f.w, c00, 0, 0, 0);    \
        c01 = __builtin_amdgcn_mfma_f64_16x16x4f64((double)a0f.w, (double)b1f.w, c01, 0, 0, 0);    \
        c10 = __builtin_amdgcn_mfma_f64_16x16x4f64((double)a1f.w, (double)b0f.w, c10, 0, 0, 0);    \
        c11 = __builtin_amdgcn_mfma_f64_16x16x4f64((double)a1f.w, (double)b1f.w, c11, 0, 0, 0);    \
        __builtin_amdgcn_s_setprio(0);                                    \
    }

    XLOAD();                             // prologue: chunk 0
    for (int chp = 0; chp < 256; ++chp) {
        XSTAGE(As0, Bt0);
        __syncthreads();
        XLOAD();
        XMFMA(As0, Bt0);
        XSTAGE(As1, Bt1);
        __syncthreads();
        if (chp + 1 < 256) { XLOAD(); }
        XMFMA(As1, Bt1);
    }
#undef XLOAD
#undef XSTAGE
#undef XMFMA

    __syncthreads();
    double* Cred = (double*)smem;        // 64*32*8 = 16384 <= 31744

#define CRED_OP(OP)                                                       \
    _Pragma("unroll")                                                     \
    for (int r = 0; r < 4; ++r) {                                         \
        const int ro = rowr[r], co = coff + colr[r];                      \
        Cred[(co     ) * 32 + ro     ] OP c00[r];                         \
        Cred[(co + 16) * 32 + ro     ] OP c01[r];                         \
        Cred[(co     ) * 32 + ro + 16] OP c10[r];                         \
        Cred[(co + 16) * 32 + ro + 16] OP c11[r];                         \
    }
    if (wid < 2)  { CRED_OP(=) }
    __syncthreads();
    if (wid >= 2) { CRED_OP(+=) }
    __syncthreads();
#undef CRED_OP

    const int scol = tid >> 2;
    const int srow = (tid & 3) * 8;
    const int tcol = tau0 + scol;
    if (tcol < T_STEPS) {
        const double* cp = &Cred[scol * 32 + srow];
        float4 o0, o1;
        o0.x = (float)cp[0]; o0.y = (float)cp[1]; o0.z = (float)cp[2]; o0.w = (float)cp[3];
        o1.x = (float)cp[4]; o1.y = (float)cp[5]; o1.z = (float)cp[6]; o1.w = (float)cp[7];
        float* op = &I0T[(size_t)tcol * N0 + n0 + srow];
        *reinterpret_cast<float4*>(op)     = o0;
        *reinterpret_cast<float4*>(op + 4) = o1;
    }
}

// ====== Kernel 1 (fallback, R9-exact): used only if ws too small for Xt ======
__global__ __launch_bounds__(256, 5) void gemm_i0_fb(const float* __restrict__ W0,
                                                     const float* __restrict__ stim,
                                                     float* __restrict__ I0T) {
    __shared__ __align__(16) char smem[27904];
    float* As0 = (float*)(smem);
    float* As1 = (float*)(smem + 4736);
    float* Bs0 = (float*)(smem + 9472);
    float* Bs1 = (float*)(smem + 18688);
    const int tid  = threadIdx.x;
    const int lane = tid & 63;
    const int wid  = tid >> 6;
    const int kbase = 16 * (wid >> 1);
    const int coff  = 32 * (wid & 1);
    const int flat = blockIdx.x;
    const int idx  = (flat & 7) * 160 + (flat >> 3);
    const int n0   = (idx / 10) * 32;
    const int tau0 = (idx % 10) * 64;
    const int r15  = lane & 15;
    const int c    = lane >> 4;
    d4 zero = {0.0, 0.0, 0.0, 0.0};
    const double ap1 = (c == 0) ? 1.0 : 0.0;
    const double bp1 = (c == 0) ? (double)r15 : 0.0;
    d4 pcol = __builtin_amdgcn_mfma_f64_16x16x4f64(ap1, bp1, zero, 0, 0, 0);
    const double ap2 = (c == 0) ? (double)r15 : 0.0;
    const double bp2 = (c == 0) ? 1.0 : 0.0;
    d4 prow = __builtin_amdgcn_mfma_f64_16x16x4f64(ap2, bp2, zero, 0, 0, 0);
    int rowr[4], colr[4];
#pragma unroll
    for (int r = 0; r < 4; ++r) {
        int cc = (int)pcol[r]; cc = cc < 0 ? 0 : (cc > 15 ? 15 : cc);
        int rw = (int)prow[r]; rw = rw < 0 ? 0 : (rw > 15 ? 15 : rw);
        colr[r] = cc; rowr[r] = rw;
    }
    const int ar  = tid >> 3;
    const int ac4 = (tid & 7) * 4;
    const int br  = tid >> 4;
    const int bc4 = (tid & 15) * 4;
    const int t0g = tau0 + bc4;
    const bool fastB = (tau0 + 68) <= T_RAW;
    const float* aP  = W0 + (size_t)(n0 + ar) * NIN + ac4;
    const float* bP0 = stim + (size_t)br * T_RAW + t0g;
    const float* bP1 = stim + (size_t)(br + 16) * T_RAW + t0g;
    float4 aR, bRa, bRb;
#define FLOAD()                                                           \
    aR = *reinterpret_cast<const float4*>(aP);                            \
    if (fastB) {                                                          \
        float4 f0 = *reinterpret_cast<const float4*>(bP0);                \
        float  e0 = bP0[4];                                               \
        bRa.x = f0.y; bRa.y = f0.z; bRa.z = f0.w; bRa.w = e0;             \
        float4 f1 = *reinterpret_cast<const float4*>(bP1);                \
        float  e1 = bP1[4];                                               \
        bRb.x = f1.y; bRb.y = f1.z; bRb.z = f1.w; bRb.w = e1;             \
    } else {                                                              \
        bRa.x = (t0g + 0 < T_STEPS) ? bP0[1] : 0.0f;                      \
        bRa.y = (t0g + 1 < T_STEPS) ? bP0[2] : 0.0f;                      \
        bRa.z = (t0g + 2 < T_STEPS) ? bP0[3] : 0.0f;                      \
        bRa.w = (t0g + 3 < T_STEPS) ? bP0[4] : 0.0f;                      \
        bRb.x = (t0g + 0 < T_STEPS) ? bP1[1] : 0.0f;                      \
        bRb.y = (t0g + 1 < T_STEPS) ? bP1[2] : 0.0f;                      \
        bRb.z = (t0g + 2 < T_STEPS) ? bP1[3] : 0.0f;                      \
        bRb.w = (t0g + 3 < T_STEPS) ? bP1[4] : 0.0f;                      \
    }                                                                     \
    aP += 32; bP0 += 32 * T_RAW; bP1 += 32 * T_RAW;
#define FSTAGE(AS, BS)                                                    \
    *reinterpret_cast<float4*>(&AS[ar * 37 + ac4]) = aR;                  \
    *reinterpret_cast<float4*>(&BS[br * 72 + bc4]) = bRa;                 \
    *reinterpret_cast<float4*>(&BS[(br + 16) * 72 + bc4]) = bRb;
#define FKSTEP(AS, BS, KK)                                                \
    {                                                                     \
        const double a0 = (double)AS[r15 * 37 + (KK)];                    \
        const double a1 = (double)AS[(16 + r15) * 37 + (KK)];             \
        const double b0 = (double)BS[(KK) * 72 + coff + r15];             \
        const double b1 = (double)BS[(KK) * 72 + coff + 16 + r15];        \
        c00 = __builtin_amdgcn_mfma_f64_16x16x4f64(a0, b0, c00, 0, 0, 0); \
        c01 = __builtin_amdgcn_mfma_f64_16x16x4f64(a0, b1, c01, 0, 0, 0); \
        c10 = __builtin_amdgcn_mfma_f64_16x16x4f64(a1, b0, c10, 0, 0, 0); \
        c11 = __builtin_amdgcn_mfma_f64_16x16x4f64(a1, b1, c11, 0, 0, 0); \
    }
#define FMFMA(AS, BS)                                                     \
    __builtin_amdgcn_s_setprio(1);                                        \
    FKSTEP(AS, BS, kbase + c);                                            \
    FKSTEP(AS, BS, kbase + 4 + c);                                        \
    FKSTEP(AS, BS, kbase + 8 + c);                                        \
    FKSTEP(AS, BS, kbase + 12 + c);                                       \
    __builtin_amdgcn_s_setprio(0);
    d4 c00 = {0,0,0,0}, c01 = {0,0,0,0};
    d4 c10 = {0,0,0,0}, c11 = {0,0,0,0};
    FLOAD();
    for (int chp = 0; chp < 256; ++chp) {
        FSTAGE(As0, Bs0);
        __syncthreads();
        FLOAD();
        FMFMA(As0, Bs0);
        FSTAGE(As1, Bs1);
        __syncthreads();
        if (chp + 1 < 256) { FLOAD(); }
        FMFMA(As1, Bs1);
    }
#undef FLOAD
#undef FSTAGE
#undef FKSTEP
#undef FMFMA
    __syncthreads();
    double* Cred = (double*)smem;
#define CRED_OP(OP)                                                       \
    _Pragma("unroll")                                                     \
    for (int r = 0; r < 4; ++r) {                                         \
        const int ro = rowr[r], co = coff + colr[r];                      \
        Cred[(co     ) * 32 + ro     ] OP c00[r];                         \
        Cred[(co + 16) * 32 + ro     ] OP c01[r];                         \
        Cred[(co     ) * 32 + ro + 16] OP c10[r];                         \
        Cred[(co + 16) * 32 + ro + 16] OP c11[r];                         \
    }
    if (wid < 2)  { CRED_OP(=) }
    __syncthreads();
    if (wid >= 2) { CRED_OP(+=) }
    __syncthreads();
#undef CRED_OP
    const int scol = tid >> 2;
    const int srow = (tid & 3) * 8;
    const int tcol = tau0 + scol;
    if (tcol < T_STEPS) {
        const double* cp = &Cred[scol * 32 + srow];
        float4 o0, o1;
        o0.x = (float)cp[0]; o0.y = (float)cp[1]; o0.z = (float)cp[2]; o0.w = (float)cp[3];
        o1.x = (float)cp[4]; o1.y = (float)cp[5]; o1.z = (float)cp[6]; o1.w = (float)cp[7];
        float* op = &I0T[(size_t)tcol * N0 + n0 + srow];
        *reinterpret_cast<float4*>(op)     = o0;
        *reinterpret_cast<float4*>(op + 4) = o1;
    }
}

// ====== Kernel 2: layer-0 LIF scan -> bitpacked S0 + fp32 S0.T output, 16-deep ======
__global__ void lif0x(const float* __restrict__ I0T, uint32_t* __restrict__ S0P,
                      float* __restrict__ out) {
#pragma clang fp contract(off)
    __shared__ float tile[64][65];
    const int l  = threadIdx.x;          // lane = local neuron
    const int n0 = blockIdx.x * 64;
    const int n  = n0 + l;
    uint32_t* rowp = S0P + n * S0W;
    rowp[0] = 0u;
    rowp[20] = 0u; rowp[21] = 0u; rowp[22] = 0u; rowp[23] = 0u;
    float v = 0.0f;
    uint32_t word = 0;
    for (int b = 0; b < 10; ++b) {
        const int tbase = b * 64;
        const int tcnt  = (tbase + 64 <= T_STEPS) ? 64 : (T_STEPS - tbase);  // 64 or 23
        int u = 0;
        for (; u + 16 <= tcnt; u += 16) {
            float I[16];
#pragma unroll
            for (int k = 0; k < 16; ++k) I[k] = I0T[(size_t)(tbase + u + k) * N0 + n];
#pragma unroll
            for (int k = 0; k < 16; ++k) {
                const int tt = tbase + u + k;
                float a = v * 0.9f;            // separate rounding (match jnp)
                v = a + I[k];
                float s = 0.0f;
                if (v >= 1.0f) { word |= (1u << (tt & 31)); v = 0.0f; s = 1.0f; }
                tile[l][u + k] = s;
                if ((tt & 31) == 31) { rowp[1 + (tt >> 5)] = word; word = 0; }
            }
        }
        for (; u < tcnt; ++u) {
            const int tt = tbase + u;
            float I = I0T[(size_t)tt * N0 + n];
            float a = v * 0.9f;
            v = a + I;
            float s = 0.0f;
            if (v >= 1.0f) { word |= (1u << (tt & 31)); v = 0.0f; s = 1.0f; }
            tile[l][u] = s;
            if ((tt & 31) == 31) { rowp[1 + (tt >> 5)] = word; word = 0; }
        }
        __syncthreads();
        if (l < tcnt) {
#pragma unroll 8
            for (int r = 0; r < 64; ++r)
                out[(size_t)(n0 + r) * T_STEPS + tbase + l] = tile[r][l];
        }
        __syncthreads();
    }
    rowp[1 + (T_STEPS >> 5)] = word;   // word 18 flush (bits 576..598)
}

// ====== Kernel 3a (fast): gather over an i-QUARTER -> fp64 partials (unroll 8) ======
__global__ __launch_bounds__(128) void gather_q(const float* __restrict__ W1,
                                                const int* __restrict__ delays,
                                                const uint32_t* __restrict__ S0P,
                                                double* __restrict__ part) {
    __shared__ double  wl[1024];    // 8 KB
    __shared__ uint8_t dl[1024];    // 1 KB
    const int bid   = blockIdx.x;           // 0..4095
    const int j     = bid >> 2;
    const int ibase = (bid & 3) * 1024;
    const int tid   = threadIdx.x;
    for (int q = tid; q < 1024 / 4; q += 128) {
        const float4 w4 = *reinterpret_cast<const float4*>(&W1[(size_t)j * N0 + ibase + 4 * q]);
        wl[4 * q + 0] = (double)w4.x; wl[4 * q + 1] = (double)w4.y;
        wl[4 * q + 2] = (double)w4.z; wl[4 * q + 3] = (double)w4.w;
        const int4 dv = *reinterpret_cast<const int4*>(&delays[(size_t)j * N0 + ibase + 4 * q]);
        dl[4 * q + 0] = (uint8_t)dv.x; dl[4 * q + 1] = (uint8_t)dv.y;
        dl[4 * q + 2] = (uint8_t)dv.z; dl[4 * q + 3] = (uint8_t)dv.w;
    }
    __syncthreads();
    const int t5 = 5 * tid;                     // 0,5,...,595 (tid<120 active)
    double a0 = 0.0, a1 = 0.0, a2 = 0.0, a3 = 0.0, a4 = 0.0;
    const uint32_t* rp0 = S0P + (size_t)ibase * S0W + 1;   // +1 folds pad word
#pragma unroll 8
    for (int i = 0; i < 1024; ++i) {
        const int s0  = t5 - (int)dl[i];        // [-15, 595]
        const double w = wl[i];
        const int widx = (s0 >> 5);             // -1..18; bias makes it valid
        const int sh   = s0 & 31;
        const uint32_t lo = rp0[widx];
        const uint32_t hi = rp0[widx + 1];
        const uint32_t w5 = (uint32_t)(((((uint64_t)hi) << 32) | lo) >> sh);
        a0 = fma((double)( w5       & 1u), w, a0);
        a1 = fma((double)((w5 >> 1) & 1u), w, a1);
        a2 = fma((double)((w5 >> 2) & 1u), w, a2);
        a3 = fma((double)((w5 >> 3) & 1u), w, a3);
        a4 = fma((double)((w5 >> 4) & 1u), w, a4);
        rp0 += S0W;
    }
    if (tid < 120) {
        double* op = part + (size_t)bid * T_STEPS + t5;
        op[0] = a0; op[1] = a1; op[2] = a2; op[3] = a3;
        if (t5 + 4 < T_STEPS) op[4] = a4;
    }
}

// ====== Kernel 4a (fast): combine 4 quarters + layer-1 LIF + S1 output ======
__global__ __launch_bounds__(64) void combine_lif1_q(const double* __restrict__ part,
                                                     float* __restrict__ out) {
#pragma clang fp contract(off)
    __shared__ float i1row[T_RAW];
    const int j = blockIdx.x;
    const int l = threadIdx.x;
    const double* p0 = part + (size_t)(4 * j)     * T_STEPS;
    const double* p1 = part + (size_t)(4 * j + 1) * T_STEPS;
    const double* p2 = part + (size_t)(4 * j + 2) * T_STEPS;
    const double* p3 = part + (size_t)(4 * j + 3) * T_STEPS;
    for (int t = l; t < T_STEPS; t += 64)
        i1row[t] = (float)(p0[t] + p1[t] + p2[t] + p3[t]);
    __syncthreads();
    if (l == 0) {
        float* o = out + (size_t)N0 * T_STEPS + (size_t)j * T_STEPS;
        float v = 0.0f;
        for (int t = 0; t < T_STEPS; ++t) {
            float a = v * 0.9f;                 // separate rounding (match jnp)
            v = a + i1row[t];
            float s = 0.0f;
            if (v >= 1.0f) { s = 1.0f; v = 0.0f; }
            o[t] = s;
        }
    }
}

// ====== Kernel 3b/4b (fallback): half-split gather into I0T region (R13-exact) ======
__global__ __launch_bounds__(128) void gather_half(const float* __restrict__ W1,
                                                   const int* __restrict__ delays,
                                                   const uint32_t* __restrict__ S0P,
                                                   double* __restrict__ part) {
    __shared__ double  wl[2048];
    __shared__ uint8_t dl[2048];
    const int bid  = blockIdx.x;
    const int j    = bid >> 1;
    const int ibase = (bid & 1) * 2048;
    const int tid  = threadIdx.x;
    for (int q = tid; q < 2048 / 4; q += 128) {
        const float4 w4 = *reinterpret_cast<const float4*>(&W1[(size_t)j * N0 + ibase + 4 * q]);
        wl[4 * q + 0] = (double)w4.x; wl[4 * q + 1] = (double)w4.y;
        wl[4 * q + 2] = (double)w4.z; wl[4 * q + 3] = (double)w4.w;
        const int4 dv = *reinterpret_cast<const int4*>(&delays[(size_t)j * N0 + ibase + 4 * q]);
        dl[4 * q + 0] = (uint8_t)dv.x; dl[4 * q + 1] = (uint8_t)dv.y;
        dl[4 * q + 2] = (uint8_t)dv.z; dl[4 * q + 3] = (uint8_t)dv.w;
    }
    __syncthreads();
    const int t5 = 5 * tid;
    double a0 = 0.0, a1 = 0.0, a2 = 0.0, a3 = 0.0, a4 = 0.0;
    const uint32_t* rp0 = S0P + (size_t)ibase * S0W + 1;
#pragma unroll 2
    for (int i = 0; i < 2048; ++i) {
        const int s0  = t5 - (int)dl[i];
        const double w = wl[i];
        const int widx = (s0 >> 5);
        const int sh   = s0 & 31;
        const uint32_t lo = rp0[widx];
        const uint32_t hi = rp0[widx + 1];
        const uint32_t w5 = (uint32_t)(((((uint64_t)hi) << 32) | lo) >> sh);
        a0 = fma((double)( w5       & 1u), w, a0);
        a1 = fma((double)((w5 >> 1) & 1u), w, a1);
        a2 = fma((double)((w5 >> 2) & 1u), w, a2);
        a3 = fma((double)((w5 >> 3) & 1u), w, a3);
        a4 = fma((double)((w5 >> 4) & 1u), w, a4);
        rp0 += S0W;
    }
    if (tid < 120) {
        double* op = part + (size_t)bid * T_STEPS + t5;
        op[0] = a0; op[1] = a1; op[2] = a2; op[3] = a3;
        if (t5 + 4 < T_STEPS) op[4] = a4;
    }
}

__global__ __launch_bounds__(64) void combine_lif1_h(const double* __restrict__ part,
                                                     float* __restrict__ out) {
#pragma clang fp contract(off)
    __shared__ float i1row[T_RAW];
    const int j = blockIdx.x;
    const int l = threadIdx.x;
    const double* p0 = part + (size_t)(2 * j)     * T_STEPS;
    const double* p1 = part + (size_t)(2 * j + 1) * T_STEPS;
    for (int t = l; t < T_STEPS; t += 64)
        i1row[t] = (float)(p0[t] + p1[t]);
    __syncthreads();
    if (l == 0) {
        float* o = out + (size_t)N0 * T_STEPS + (size_t)j * T_STEPS;
        float v = 0.0f;
        for (int t = 0; t < T_STEPS; ++t) {
            float a = v * 0.9f;
            v = a + i1row[t];
            float s = 0.0f;
            if (v >= 1.0f) { s = 1.0f; v = 0.0f; }
            o[t] = s;
        }
    }
}

extern "C" void kernel_launch(void* const* d_in, const int* in_sizes, int n_in,
                              void* d_out, int out_size, void* d_ws, size_t ws_size,
                              hipStream_t stream) {
    const float* stim   = (const float*)d_in[0];   // 128*128*600
    const float* W0     = (const float*)d_in[1];   // 4096*16384
    const float* W1     = (const float*)d_in[2];   // 1024*4096
    const int*   delays = (const int*)d_in[3];     // 1024*4096

    char* ws = (char*)d_ws;
    float*    I0T   = (float*)(ws + OFF_I0T);
    uint32_t* S0b   = (uint32_t*)(ws + OFF_S0B);
    float*    Xt    = (float*)(ws + OFF_XT);
    double*   partQ = (double*)(ws + OFF_XT);      // reuses Xt region after gemm
    double*   partH = (double*)(ws + OFF_I0T);     // reuses I0T region (fallback)
    float*    out   = (float*)d_out;

    if (ws_size >= OFF_XT + SZ_XT) {
        hipLaunchKernelGGL(transpose_stim, dim3(10, 256), dim3(256), 0, stream, stim, Xt);
        hipLaunchKernelGGL(gemm_i0_xt,     dim3(1280),    dim3(256), 0, stream, W0, Xt, I0T);
        hipLaunchKernelGGL(lif0x,          dim3(64),      dim3(64),  0, stream, I0T, S0b, out);
        hipLaunchKernelGGL(gather_q,       dim3(4096),    dim3(128), 0, stream, W1, delays, S0b, partQ);
        hipLaunchKernelGGL(combine_lif1_q, dim3(1024),    dim3(64),  0, stream, partQ, out);
    } else {
        hipLaunchKernelGGL(gemm_i0_fb,     dim3(1280),    dim3(256), 0, stream, W0, stim, I0T);
        hipLaunchKernelGGL(lif0x,          dim3(64),      dim3(64),  0, stream, I0T, S0b, out);
        hipLaunchKernelGGL(gather_half,    dim3(2048),    dim3(128), 0, stream, W1, delays, S0b, partH);
        hipLaunchKernelGGL(combine_lif1_h, dim3(1024),    dim3(64),  0, stream, partH, out);
    }
}